// Round 1
// baseline (2324.684 us; speedup 1.0000x reference)
//
#include <hip/hip_runtime.h>
#include <cstddef>

#define NN    100000
#define EE    1600000
#define F1D   512
#define F3D   128
#define HD    128
#define CD    64
#define SWc   0.2f
#define FWc   0.8f
#define BN_EPS 1e-5f

// ---------------------------------------------------------------------------
// GEMM1 (fused): h = FW*(x1@W1+b1) + SW*(x2@W2+b2);  z = h @ Wg1
// Block: 256 threads (16x16), tile M=64 rows x 128 cols, each thread 4x8.
// ---------------------------------------------------------------------------
__global__ __launch_bounds__(256) void gemm1_kernel(
    const float* __restrict__ x1, const float* __restrict__ x2,
    const float* __restrict__ W1, const float* __restrict__ b1,
    const float* __restrict__ W2, const float* __restrict__ b2,
    const float* __restrict__ Wg1, float* __restrict__ z)
{
    __shared__ float As[16][64];     // A chunk, transposed: As[kk][row]
    __shared__ float Bs[16][128];    // B chunk: Bs[kk][col]
    __shared__ float Hs[64][132];    // h tile (pad 132 to break bank conflicts)

    const int tid = threadIdx.x;
    const int tx = tid & 15;         // col group
    const int ty = tid >> 4;         // row group
    const int row0 = blockIdx.x * 64;

    const int lr = tid >> 2;          // 0..63  (A-stage row)
    const int lk = (tid & 3) * 4;     // 0,4,8,12 (A-stage k quad)
    const int grow_l = row0 + lr;
    const int bk = tid >> 4;          // 0..15  (B-stage k)
    const int bc = (tid & 15) * 8;    // B-stage col

    float acc[4][8];
#pragma unroll
    for (int i = 0; i < 4; ++i)
#pragma unroll
        for (int j = 0; j < 8; ++j) acc[i][j] = 0.f;

    // ---- Part 1: x1 @ (FW*W1), K = 512 ----
    for (int k0 = 0; k0 < F1D; k0 += 16) {
        float4 av = make_float4(0.f, 0.f, 0.f, 0.f);
        if (grow_l < NN)
            av = *(const float4*)(x1 + (size_t)grow_l * F1D + k0 + lk);
        As[lk + 0][lr] = av.x; As[lk + 1][lr] = av.y;
        As[lk + 2][lr] = av.z; As[lk + 3][lr] = av.w;

        const float* wp = W1 + (size_t)(k0 + bk) * HD + bc;
        float4 w0 = *(const float4*)wp;
        float4 w1 = *(const float4*)(wp + 4);
        Bs[bk][bc + 0] = w0.x * FWc; Bs[bk][bc + 1] = w0.y * FWc;
        Bs[bk][bc + 2] = w0.z * FWc; Bs[bk][bc + 3] = w0.w * FWc;
        Bs[bk][bc + 4] = w1.x * FWc; Bs[bk][bc + 5] = w1.y * FWc;
        Bs[bk][bc + 6] = w1.z * FWc; Bs[bk][bc + 7] = w1.w * FWc;
        __syncthreads();
#pragma unroll
        for (int kk = 0; kk < 16; ++kk) {
            float4 a  = *(const float4*)&As[kk][ty * 4];
            float4 b0 = *(const float4*)&Bs[kk][tx * 8];
            float4 b1v= *(const float4*)&Bs[kk][tx * 8 + 4];
            float aa[4] = {a.x, a.y, a.z, a.w};
            float bb[8] = {b0.x, b0.y, b0.z, b0.w, b1v.x, b1v.y, b1v.z, b1v.w};
#pragma unroll
            for (int i = 0; i < 4; ++i)
#pragma unroll
                for (int j = 0; j < 8; ++j)
                    acc[i][j] = fmaf(aa[i], bb[j], acc[i][j]);
        }
        __syncthreads();
    }

    // ---- Part 2: x2 @ (SW*W2), K = 128 ----
    for (int k0 = 0; k0 < F3D; k0 += 16) {
        float4 av = make_float4(0.f, 0.f, 0.f, 0.f);
        if (grow_l < NN)
            av = *(const float4*)(x2 + (size_t)grow_l * F3D + k0 + lk);
        As[lk + 0][lr] = av.x; As[lk + 1][lr] = av.y;
        As[lk + 2][lr] = av.z; As[lk + 3][lr] = av.w;

        const float* wp = W2 + (size_t)(k0 + bk) * HD + bc;
        float4 w0 = *(const float4*)wp;
        float4 w1 = *(const float4*)(wp + 4);
        Bs[bk][bc + 0] = w0.x * SWc; Bs[bk][bc + 1] = w0.y * SWc;
        Bs[bk][bc + 2] = w0.z * SWc; Bs[bk][bc + 3] = w0.w * SWc;
        Bs[bk][bc + 4] = w1.x * SWc; Bs[bk][bc + 5] = w1.y * SWc;
        Bs[bk][bc + 6] = w1.z * SWc; Bs[bk][bc + 7] = w1.w * SWc;
        __syncthreads();
#pragma unroll
        for (int kk = 0; kk < 16; ++kk) {
            float4 a  = *(const float4*)&As[kk][ty * 4];
            float4 b0 = *(const float4*)&Bs[kk][tx * 8];
            float4 b1v= *(const float4*)&Bs[kk][tx * 8 + 4];
            float aa[4] = {a.x, a.y, a.z, a.w};
            float bb[8] = {b0.x, b0.y, b0.z, b0.w, b1v.x, b1v.y, b1v.z, b1v.w};
#pragma unroll
            for (int i = 0; i < 4; ++i)
#pragma unroll
                for (int j = 0; j < 8; ++j)
                    acc[i][j] = fmaf(aa[i], bb[j], acc[i][j]);
        }
        __syncthreads();
    }

    // ---- bias, stash h tile into LDS ----
    {
        float4 c10 = *(const float4*)(b1 + tx * 8);
        float4 c11 = *(const float4*)(b1 + tx * 8 + 4);
        float4 c20 = *(const float4*)(b2 + tx * 8);
        float4 c21 = *(const float4*)(b2 + tx * 8 + 4);
        float hb[8] = {FWc*c10.x + SWc*c20.x, FWc*c10.y + SWc*c20.y,
                       FWc*c10.z + SWc*c20.z, FWc*c10.w + SWc*c20.w,
                       FWc*c11.x + SWc*c21.x, FWc*c11.y + SWc*c21.y,
                       FWc*c11.z + SWc*c21.z, FWc*c11.w + SWc*c21.w};
#pragma unroll
        for (int i = 0; i < 4; ++i)
#pragma unroll
            for (int j = 0; j < 8; ++j)
                Hs[ty * 4 + i][tx * 8 + j] = acc[i][j] + hb[j];
    }

    // ---- Phase 2: z = h @ Wg1, K = 128 ----
    float acc2[4][8];
#pragma unroll
    for (int i = 0; i < 4; ++i)
#pragma unroll
        for (int j = 0; j < 8; ++j) acc2[i][j] = 0.f;

    for (int k0 = 0; k0 < HD; k0 += 16) {
        const float* wp = Wg1 + (size_t)(k0 + bk) * HD + bc;
        float4 w0 = *(const float4*)wp;
        float4 w1 = *(const float4*)(wp + 4);
        Bs[bk][bc + 0] = w0.x; Bs[bk][bc + 1] = w0.y;
        Bs[bk][bc + 2] = w0.z; Bs[bk][bc + 3] = w0.w;
        Bs[bk][bc + 4] = w1.x; Bs[bk][bc + 5] = w1.y;
        Bs[bk][bc + 6] = w1.z; Bs[bk][bc + 7] = w1.w;
        __syncthreads();   // also covers the Hs writes on first iteration
#pragma unroll
        for (int kk = 0; kk < 16; ++kk) {
            float aa[4];
#pragma unroll
            for (int i = 0; i < 4; ++i) aa[i] = Hs[ty * 4 + i][k0 + kk];
            float4 b0 = *(const float4*)&Bs[kk][tx * 8];
            float4 b1v= *(const float4*)&Bs[kk][tx * 8 + 4];
            float bb[8] = {b0.x, b0.y, b0.z, b0.w, b1v.x, b1v.y, b1v.z, b1v.w};
#pragma unroll
            for (int i = 0; i < 4; ++i)
#pragma unroll
                for (int j = 0; j < 8; ++j)
                    acc2[i][j] = fmaf(aa[i], bb[j], acc2[i][j]);
        }
        __syncthreads();
    }

    // ---- store z ----
#pragma unroll
    for (int i = 0; i < 4; ++i) {
        int r = row0 + ty * 4 + i;
        if (r < NN) {
            float4 o0 = make_float4(acc2[i][0], acc2[i][1], acc2[i][2], acc2[i][3]);
            float4 o1 = make_float4(acc2[i][4], acc2[i][5], acc2[i][6], acc2[i][7]);
            *(float4*)(z + (size_t)r * HD + tx * 8)     = o0;
            *(float4*)(z + (size_t)r * HD + tx * 8 + 4) = o1;
        }
    }
}

// ---------------------------------------------------------------------------
// Scatter 1: agg[dst[e]] += z[src[e]]  (H=128 floats; 1 wave per edge,
// lane l handles features 2l, 2l+1)
// ---------------------------------------------------------------------------
__global__ __launch_bounds__(256) void scatter1_kernel(
    const float* __restrict__ z, const int* __restrict__ src,
    const int* __restrict__ dst, float* __restrict__ agg)
{
    int e = blockIdx.x * 4 + (threadIdx.x >> 6);
    if (e >= EE) return;
    int lane = threadIdx.x & 63;
    int s = src[e], d = dst[e];
    float2 v = *(const float2*)(z + (size_t)s * HD + lane * 2);
    float* p = agg + (size_t)d * HD + lane * 2;
    unsafeAtomicAdd(p,     v.x);
    unsafeAtomicAdd(p + 1, v.y);
}

// ---------------------------------------------------------------------------
// GEMM2 (fused BN+ReLU): z2 = relu(agg*s + t) @ Wg2
// Block 256 (16x16), tile M=64 x N=64, each thread 4x4.
// ---------------------------------------------------------------------------
__global__ __launch_bounds__(256) void gemm2_kernel(
    const float* __restrict__ agg, const float* __restrict__ Wg2,
    const float* __restrict__ bg1, const float* __restrict__ gamma,
    const float* __restrict__ beta, const float* __restrict__ rmean,
    const float* __restrict__ rvar, float* __restrict__ z2)
{
    __shared__ float As[16][64];
    __shared__ float Bs[16][64];
    __shared__ float sS[HD];
    __shared__ float sT[HD];

    const int tid = threadIdx.x;
    if (tid < HD) {
        float s = gamma[tid] * rsqrtf(rvar[tid] + BN_EPS);
        sS[tid] = s;
        sT[tid] = (bg1[tid] - rmean[tid]) * s + beta[tid];
    }
    __syncthreads();

    const int tx = tid & 15, ty = tid >> 4;
    const int row0 = blockIdx.x * 64;
    const int lr = tid >> 2;
    const int lk = (tid & 3) * 4;
    const int grow_l = row0 + lr;
    const int bk = tid >> 4;
    const int bc = (tid & 15) * 4;

    float acc[4][4];
#pragma unroll
    for (int i = 0; i < 4; ++i)
#pragma unroll
        for (int j = 0; j < 4; ++j) acc[i][j] = 0.f;

    for (int k0 = 0; k0 < HD; k0 += 16) {
        float4 av = make_float4(0.f, 0.f, 0.f, 0.f);
        if (grow_l < NN)
            av = *(const float4*)(agg + (size_t)grow_l * HD + k0 + lk);
        av.x = fmaxf(fmaf(av.x, sS[k0 + lk + 0], sT[k0 + lk + 0]), 0.f);
        av.y = fmaxf(fmaf(av.y, sS[k0 + lk + 1], sT[k0 + lk + 1]), 0.f);
        av.z = fmaxf(fmaf(av.z, sS[k0 + lk + 2], sT[k0 + lk + 2]), 0.f);
        av.w = fmaxf(fmaf(av.w, sS[k0 + lk + 3], sT[k0 + lk + 3]), 0.f);
        As[lk + 0][lr] = av.x; As[lk + 1][lr] = av.y;
        As[lk + 2][lr] = av.z; As[lk + 3][lr] = av.w;

        float4 wv = *(const float4*)(Wg2 + (size_t)(k0 + bk) * CD + bc);
        Bs[bk][bc + 0] = wv.x; Bs[bk][bc + 1] = wv.y;
        Bs[bk][bc + 2] = wv.z; Bs[bk][bc + 3] = wv.w;
        __syncthreads();
#pragma unroll
        for (int kk = 0; kk < 16; ++kk) {
            float4 a = *(const float4*)&As[kk][ty * 4];
            float4 b = *(const float4*)&Bs[kk][tx * 4];
            float aa[4] = {a.x, a.y, a.z, a.w};
            float bb[4] = {b.x, b.y, b.z, b.w};
#pragma unroll
            for (int i = 0; i < 4; ++i)
#pragma unroll
                for (int j = 0; j < 4; ++j)
                    acc[i][j] = fmaf(aa[i], bb[j], acc[i][j]);
        }
        __syncthreads();
    }

#pragma unroll
    for (int i = 0; i < 4; ++i) {
        int r = row0 + ty * 4 + i;
        if (r < NN) {
            float4 o = make_float4(acc[i][0], acc[i][1], acc[i][2], acc[i][3]);
            *(float4*)(z2 + (size_t)r * CD + tx * 4) = o;
        }
    }
}

// ---------------------------------------------------------------------------
// Scatter 2: out[dst[e]] += z2[src[e]]  (C=64; 1 wave per edge, lane = feat)
// ---------------------------------------------------------------------------
__global__ __launch_bounds__(256) void scatter2_kernel(
    const float* __restrict__ z2, const int* __restrict__ src,
    const int* __restrict__ dst, float* __restrict__ out)
{
    int e = blockIdx.x * 4 + (threadIdx.x >> 6);
    if (e >= EE) return;
    int lane = threadIdx.x & 63;
    int s = src[e], d = dst[e];
    float v = z2[(size_t)s * CD + lane];
    unsafeAtomicAdd(out + (size_t)d * CD + lane, v);
}

// out[i][c] = bg2[c] (bias init before scatter2)
__global__ __launch_bounds__(256) void init_out_kernel(
    const float* __restrict__ bg2, float* __restrict__ out)
{
    int i = blockIdx.x * 256 + threadIdx.x;
    if (i < NN * CD) out[i] = bg2[i & (CD - 1)];
}

extern "C" void kernel_launch(void* const* d_in, const int* in_sizes, int n_in,
                              void* d_out, int out_size, void* d_ws, size_t ws_size,
                              hipStream_t stream)
{
    const float* x1    = (const float*)d_in[0];
    const float* x2    = (const float*)d_in[1];
    const int*   ei    = (const int*)d_in[2];
    const float* W1    = (const float*)d_in[3];
    const float* b1    = (const float*)d_in[4];
    const float* W2    = (const float*)d_in[5];
    const float* b2    = (const float*)d_in[6];
    const float* Wg1   = (const float*)d_in[7];
    const float* bg1   = (const float*)d_in[8];
    const float* Wg2   = (const float*)d_in[9];
    const float* bg2   = (const float*)d_in[10];
    const float* gamma = (const float*)d_in[11];
    const float* beta  = (const float*)d_in[12];
    const float* rmean = (const float*)d_in[13];
    const float* rvar  = (const float*)d_in[14];
    float* out = (float*)d_out;

    float* z   = (float*)d_ws;                 // N*H floats (51.2 MB)
    float* agg = z + (size_t)NN * HD;          // N*H floats (51.2 MB)
    float* z2  = z;                            // reuse z region after scatter1

    const int* src = ei;
    const int* dst = ei + EE;

    hipMemsetAsync(agg, 0, (size_t)NN * HD * sizeof(float), stream);
    init_out_kernel<<<(NN * CD + 255) / 256, 256, 0, stream>>>(bg2, out);
    gemm1_kernel<<<(NN + 63) / 64, 256, 0, stream>>>(x1, x2, W1, b1, W2, b2, Wg1, z);
    scatter1_kernel<<<(EE + 3) / 4, 256, 0, stream>>>(z, src, dst, agg);
    gemm2_kernel<<<(NN + 63) / 64, 256, 0, stream>>>(agg, Wg2, bg1, gamma, beta,
                                                     rmean, rvar, z2);
    scatter2_kernel<<<(EE + 3) / 4, 256, 0, stream>>>(z2, src, dst, out);
}

// Round 2
// 1347.853 us; speedup vs baseline: 1.7247x; 1.7247x over previous
//
#include <hip/hip_runtime.h>
#include <hip/hip_fp16.h>
#include <cstddef>

#define NN    100000
#define EE    1600000
#define F1D   512
#define F3D   128
#define HD    128
#define CD    64
#define SWc   0.2f
#define FWc   0.8f
#define BN_EPS 1e-5f

// ===========================================================================
// CSR build: deg-count -> single-block scan -> atomic-cursor fill
// ===========================================================================
__global__ __launch_bounds__(256) void count_kernel(
    const int* __restrict__ dst, int* __restrict__ deg)
{
    int e = blockIdx.x * 256 + threadIdx.x;
    if (e < EE) atomicAdd(&deg[dst[e]], 1);
}

// 1 block, 1024 threads. In-place exclusive scan of deg[0..N-1] -> offsets,
// duplicate into cursor, total -> offsets[N].
__global__ __launch_bounds__(1024) void scan_kernel(
    int* __restrict__ offsets, int* __restrict__ cursor)
{
    const int T = 1024;
    const int tid = threadIdx.x;
    const int per = (NN + T - 1) / T;   // 98
    int lo = tid * per;
    int hi = lo + per; if (hi > NN) hi = NN; if (lo > NN) lo = NN;

    int sum = 0;
    for (int i = lo; i < hi; ++i) sum += offsets[i];

    __shared__ int sh[T];
    sh[tid] = sum;
    __syncthreads();
    for (int d = 1; d < T; d <<= 1) {
        int v = (tid >= d) ? sh[tid - d] : 0;
        __syncthreads();
        sh[tid] += v;
        __syncthreads();
    }
    int run = (tid == 0) ? 0 : sh[tid - 1];
    for (int i = lo; i < hi; ++i) {
        int d = offsets[i];
        offsets[i] = run;
        cursor[i]  = run;
        run += d;
    }
    if (tid == T - 1) offsets[NN] = run;   // == EE
}

__global__ __launch_bounds__(256) void fill_kernel(
    const int* __restrict__ src, const int* __restrict__ dst,
    int* __restrict__ cursor, int* __restrict__ csr_src)
{
    int e = blockIdx.x * 256 + threadIdx.x;
    if (e < EE) {
        int d = dst[e];
        int pos = atomicAdd(&cursor[d], 1);
        csr_src[pos] = src[e];
    }
}

// ===========================================================================
// GEMM1 (fused): h = FW*(x1@W1+b1) + SW*(x2@W2+b2);  z = h @ Wg1  (fp16 out)
// Block 256 (16x16), tile M=64 x N=128, each thread 4x8.
// ===========================================================================
__global__ __launch_bounds__(256) void gemm1_kernel(
    const float* __restrict__ x1, const float* __restrict__ x2,
    const float* __restrict__ W1, const float* __restrict__ b1,
    const float* __restrict__ W2, const float* __restrict__ b2,
    const float* __restrict__ Wg1, __half* __restrict__ z)
{
    __shared__ float As[16][64];
    __shared__ float Bs[16][128];
    __shared__ float Hs[64][132];

    const int tid = threadIdx.x;
    const int tx = tid & 15;
    const int ty = tid >> 4;
    const int row0 = blockIdx.x * 64;

    const int lr = tid >> 2;
    const int lk = (tid & 3) * 4;
    const int grow_l = row0 + lr;
    const int bk = tid >> 4;
    const int bc = (tid & 15) * 8;

    float acc[4][8];
#pragma unroll
    for (int i = 0; i < 4; ++i)
#pragma unroll
        for (int j = 0; j < 8; ++j) acc[i][j] = 0.f;

    // ---- Part 1: x1 @ (FW*W1), K = 512 ----
    for (int k0 = 0; k0 < F1D; k0 += 16) {
        float4 av = make_float4(0.f, 0.f, 0.f, 0.f);
        if (grow_l < NN)
            av = *(const float4*)(x1 + (size_t)grow_l * F1D + k0 + lk);
        As[lk + 0][lr] = av.x; As[lk + 1][lr] = av.y;
        As[lk + 2][lr] = av.z; As[lk + 3][lr] = av.w;

        const float* wp = W1 + (size_t)(k0 + bk) * HD + bc;
        float4 w0 = *(const float4*)wp;
        float4 w1 = *(const float4*)(wp + 4);
        Bs[bk][bc + 0] = w0.x * FWc; Bs[bk][bc + 1] = w0.y * FWc;
        Bs[bk][bc + 2] = w0.z * FWc; Bs[bk][bc + 3] = w0.w * FWc;
        Bs[bk][bc + 4] = w1.x * FWc; Bs[bk][bc + 5] = w1.y * FWc;
        Bs[bk][bc + 6] = w1.z * FWc; Bs[bk][bc + 7] = w1.w * FWc;
        __syncthreads();
#pragma unroll
        for (int kk = 0; kk < 16; ++kk) {
            float4 a  = *(const float4*)&As[kk][ty * 4];
            float4 b0 = *(const float4*)&Bs[kk][tx * 8];
            float4 b1v= *(const float4*)&Bs[kk][tx * 8 + 4];
            float aa[4] = {a.x, a.y, a.z, a.w};
            float bb[8] = {b0.x, b0.y, b0.z, b0.w, b1v.x, b1v.y, b1v.z, b1v.w};
#pragma unroll
            for (int i = 0; i < 4; ++i)
#pragma unroll
                for (int j = 0; j < 8; ++j)
                    acc[i][j] = fmaf(aa[i], bb[j], acc[i][j]);
        }
        __syncthreads();
    }

    // ---- Part 2: x2 @ (SW*W2), K = 128 ----
    for (int k0 = 0; k0 < F3D; k0 += 16) {
        float4 av = make_float4(0.f, 0.f, 0.f, 0.f);
        if (grow_l < NN)
            av = *(const float4*)(x2 + (size_t)grow_l * F3D + k0 + lk);
        As[lk + 0][lr] = av.x; As[lk + 1][lr] = av.y;
        As[lk + 2][lr] = av.z; As[lk + 3][lr] = av.w;

        const float* wp = W2 + (size_t)(k0 + bk) * HD + bc;
        float4 w0 = *(const float4*)wp;
        float4 w1 = *(const float4*)(wp + 4);
        Bs[bk][bc + 0] = w0.x * SWc; Bs[bk][bc + 1] = w0.y * SWc;
        Bs[bk][bc + 2] = w0.z * SWc; Bs[bk][bc + 3] = w0.w * SWc;
        Bs[bk][bc + 4] = w1.x * SWc; Bs[bk][bc + 5] = w1.y * SWc;
        Bs[bk][bc + 6] = w1.z * SWc; Bs[bk][bc + 7] = w1.w * SWc;
        __syncthreads();
#pragma unroll
        for (int kk = 0; kk < 16; ++kk) {
            float4 a  = *(const float4*)&As[kk][ty * 4];
            float4 b0 = *(const float4*)&Bs[kk][tx * 8];
            float4 b1v= *(const float4*)&Bs[kk][tx * 8 + 4];
            float aa[4] = {a.x, a.y, a.z, a.w};
            float bb[8] = {b0.x, b0.y, b0.z, b0.w, b1v.x, b1v.y, b1v.z, b1v.w};
#pragma unroll
            for (int i = 0; i < 4; ++i)
#pragma unroll
                for (int j = 0; j < 8; ++j)
                    acc[i][j] = fmaf(aa[i], bb[j], acc[i][j]);
        }
        __syncthreads();
    }

    // ---- bias, stash h tile into LDS ----
    {
        float4 c10 = *(const float4*)(b1 + tx * 8);
        float4 c11 = *(const float4*)(b1 + tx * 8 + 4);
        float4 c20 = *(const float4*)(b2 + tx * 8);
        float4 c21 = *(const float4*)(b2 + tx * 8 + 4);
        float hb[8] = {FWc*c10.x + SWc*c20.x, FWc*c10.y + SWc*c20.y,
                       FWc*c10.z + SWc*c20.z, FWc*c10.w + SWc*c20.w,
                       FWc*c11.x + SWc*c21.x, FWc*c11.y + SWc*c21.y,
                       FWc*c11.z + SWc*c21.z, FWc*c11.w + SWc*c21.w};
#pragma unroll
        for (int i = 0; i < 4; ++i)
#pragma unroll
            for (int j = 0; j < 8; ++j)
                Hs[ty * 4 + i][tx * 8 + j] = acc[i][j] + hb[j];
    }

    // ---- Phase 2: z = h @ Wg1, K = 128 ----
    float acc2[4][8];
#pragma unroll
    for (int i = 0; i < 4; ++i)
#pragma unroll
        for (int j = 0; j < 8; ++j) acc2[i][j] = 0.f;

    for (int k0 = 0; k0 < HD; k0 += 16) {
        const float* wp = Wg1 + (size_t)(k0 + bk) * HD + bc;
        float4 w0 = *(const float4*)wp;
        float4 w1 = *(const float4*)(wp + 4);
        Bs[bk][bc + 0] = w0.x; Bs[bk][bc + 1] = w0.y;
        Bs[bk][bc + 2] = w0.z; Bs[bk][bc + 3] = w0.w;
        Bs[bk][bc + 4] = w1.x; Bs[bk][bc + 5] = w1.y;
        Bs[bk][bc + 6] = w1.z; Bs[bk][bc + 7] = w1.w;
        __syncthreads();
#pragma unroll
        for (int kk = 0; kk < 16; ++kk) {
            float aa[4];
#pragma unroll
            for (int i = 0; i < 4; ++i) aa[i] = Hs[ty * 4 + i][k0 + kk];
            float4 b0 = *(const float4*)&Bs[kk][tx * 8];
            float4 b1v= *(const float4*)&Bs[kk][tx * 8 + 4];
            float bb[8] = {b0.x, b0.y, b0.z, b0.w, b1v.x, b1v.y, b1v.z, b1v.w};
#pragma unroll
            for (int i = 0; i < 4; ++i)
#pragma unroll
                for (int j = 0; j < 8; ++j)
                    acc2[i][j] = fmaf(aa[i], bb[j], acc2[i][j]);
        }
        __syncthreads();
    }

    // ---- store z as fp16 (16B per thread-row-segment) ----
#pragma unroll
    for (int i = 0; i < 4; ++i) {
        int r = row0 + ty * 4 + i;
        if (r < NN) {
            __half hb8[8];
#pragma unroll
            for (int j = 0; j < 8; ++j) hb8[j] = __float2half(acc2[i][j]);
            *(float4*)(z + (size_t)r * HD + tx * 8) = *(float4*)hb8;
        }
    }
}

// ===========================================================================
// Gather 1: agg[n] = sum_{e: dst[e]=n} z[src[e]]   (1 wave per node,
// lane l holds features 2l, 2l+1 as __half2)
// ===========================================================================
__global__ __launch_bounds__(256) void gather1_kernel(
    const __half* __restrict__ z, const int* __restrict__ offsets,
    const int* __restrict__ csr_src, float* __restrict__ agg)
{
    int node = blockIdx.x * 4 + (threadIdx.x >> 6);
    if (node >= NN) return;
    int lane = threadIdx.x & 63;
    int beg = offsets[node], end = offsets[node + 1];
    float sx = 0.f, sy = 0.f;
    for (int j = beg; j < end; ++j) {
        int s = csr_src[j];
        __half2 v = *(const __half2*)(z + (size_t)s * HD + lane * 2);
        float2 f = __half22float2(v);
        sx += f.x; sy += f.y;
    }
    *(float2*)(agg + (size_t)node * HD + lane * 2) = make_float2(sx, sy);
}

// ===========================================================================
// GEMM2 (fused BN+ReLU): z2 = relu(agg*s + t) @ Wg2  (fp16 out)
// ===========================================================================
__global__ __launch_bounds__(256) void gemm2_kernel(
    const float* __restrict__ agg, const float* __restrict__ Wg2,
    const float* __restrict__ bg1, const float* __restrict__ gamma,
    const float* __restrict__ beta, const float* __restrict__ rmean,
    const float* __restrict__ rvar, __half* __restrict__ z2)
{
    __shared__ float As[16][64];
    __shared__ float Bs[16][64];
    __shared__ float sS[HD];
    __shared__ float sT[HD];

    const int tid = threadIdx.x;
    if (tid < HD) {
        float s = gamma[tid] * rsqrtf(rvar[tid] + BN_EPS);
        sS[tid] = s;
        sT[tid] = (bg1[tid] - rmean[tid]) * s + beta[tid];
    }
    __syncthreads();

    const int tx = tid & 15, ty = tid >> 4;
    const int row0 = blockIdx.x * 64;
    const int lr = tid >> 2;
    const int lk = (tid & 3) * 4;
    const int grow_l = row0 + lr;
    const int bk = tid >> 4;
    const int bc = (tid & 15) * 4;

    float acc[4][4];
#pragma unroll
    for (int i = 0; i < 4; ++i)
#pragma unroll
        for (int j = 0; j < 4; ++j) acc[i][j] = 0.f;

    for (int k0 = 0; k0 < HD; k0 += 16) {
        float4 av = make_float4(0.f, 0.f, 0.f, 0.f);
        if (grow_l < NN)
            av = *(const float4*)(agg + (size_t)grow_l * HD + k0 + lk);
        av.x = fmaxf(fmaf(av.x, sS[k0 + lk + 0], sT[k0 + lk + 0]), 0.f);
        av.y = fmaxf(fmaf(av.y, sS[k0 + lk + 1], sT[k0 + lk + 1]), 0.f);
        av.z = fmaxf(fmaf(av.z, sS[k0 + lk + 2], sT[k0 + lk + 2]), 0.f);
        av.w = fmaxf(fmaf(av.w, sS[k0 + lk + 3], sT[k0 + lk + 3]), 0.f);
        As[lk + 0][lr] = av.x; As[lk + 1][lr] = av.y;
        As[lk + 2][lr] = av.z; As[lk + 3][lr] = av.w;

        float4 wv = *(const float4*)(Wg2 + (size_t)(k0 + bk) * CD + bc);
        Bs[bk][bc + 0] = wv.x; Bs[bk][bc + 1] = wv.y;
        Bs[bk][bc + 2] = wv.z; Bs[bk][bc + 3] = wv.w;
        __syncthreads();
#pragma unroll
        for (int kk = 0; kk < 16; ++kk) {
            float4 a = *(const float4*)&As[kk][ty * 4];
            float4 b = *(const float4*)&Bs[kk][tx * 4];
            float aa[4] = {a.x, a.y, a.z, a.w};
            float bb[4] = {b.x, b.y, b.z, b.w};
#pragma unroll
            for (int i = 0; i < 4; ++i)
#pragma unroll
                for (int j = 0; j < 4; ++j)
                    acc[i][j] = fmaf(aa[i], bb[j], acc[i][j]);
        }
        __syncthreads();
    }

#pragma unroll
    for (int i = 0; i < 4; ++i) {
        int r = row0 + ty * 4 + i;
        if (r < NN) {
            __half hb4[4];
#pragma unroll
            for (int j = 0; j < 4; ++j) hb4[j] = __float2half(acc[i][j]);
            *(float2*)(z2 + (size_t)r * CD + tx * 4) = *(float2*)hb4;
        }
    }
}

// ===========================================================================
// Gather 2: out[n] = bg2 + sum_{e: dst[e]=n} z2[src[e]]  (1 wave/node, lane=c)
// ===========================================================================
__global__ __launch_bounds__(256) void gather2_kernel(
    const __half* __restrict__ z2, const int* __restrict__ offsets,
    const int* __restrict__ csr_src, const float* __restrict__ bg2,
    float* __restrict__ out)
{
    int node = blockIdx.x * 4 + (threadIdx.x >> 6);
    if (node >= NN) return;
    int lane = threadIdx.x & 63;
    int beg = offsets[node], end = offsets[node + 1];
    float s = bg2[lane];
    for (int j = beg; j < end; ++j) {
        int sn = csr_src[j];
        s += __half2float(z2[(size_t)sn * CD + lane]);
    }
    out[(size_t)node * CD + lane] = s;
}

// ===========================================================================
extern "C" void kernel_launch(void* const* d_in, const int* in_sizes, int n_in,
                              void* d_out, int out_size, void* d_ws, size_t ws_size,
                              hipStream_t stream)
{
    const float* x1    = (const float*)d_in[0];
    const float* x2    = (const float*)d_in[1];
    const int*   ei    = (const int*)d_in[2];
    const float* W1    = (const float*)d_in[3];
    const float* b1    = (const float*)d_in[4];
    const float* W2    = (const float*)d_in[5];
    const float* b2    = (const float*)d_in[6];
    const float* Wg1   = (const float*)d_in[7];
    const float* bg1   = (const float*)d_in[8];
    const float* Wg2   = (const float*)d_in[9];
    const float* bg2   = (const float*)d_in[10];
    const float* gamma = (const float*)d_in[11];
    const float* beta  = (const float*)d_in[12];
    const float* rmean = (const float*)d_in[13];
    const float* rvar  = (const float*)d_in[14];
    float* out = (float*)d_out;

    // ---- workspace layout (bytes): total ~84 MB ----
    char* p = (char*)d_ws;
    __half* z_h   = (__half*)p;                 p += (size_t)NN * HD * sizeof(__half);  // 25.6 MB
    float*  agg   = (float*)p;                  p += (size_t)NN * HD * sizeof(float);   // 51.2 MB
    int*    csr   = (int*)p;                    p += (size_t)EE * sizeof(int);          // 6.4 MB
    int*    offs  = (int*)p;                    p += (size_t)(NN + 1) * sizeof(int);
    int*    curs  = (int*)p;                    p += (size_t)NN * sizeof(int);
    __half* z2_h  = z_h;   // overlay: z dead after gather1

    const int* src = ei;
    const int* dst = ei + EE;

    // CSR build
    hipMemsetAsync(offs, 0, (size_t)(NN + 1) * sizeof(int), stream);
    count_kernel<<<(EE + 255) / 256, 256, 0, stream>>>(dst, offs);
    scan_kernel<<<1, 1024, 0, stream>>>(offs, curs);
    fill_kernel<<<(EE + 255) / 256, 256, 0, stream>>>(src, dst, curs, csr);

    // Pipeline
    gemm1_kernel<<<(NN + 63) / 64, 256, 0, stream>>>(x1, x2, W1, b1, W2, b2, Wg1, z_h);
    gather1_kernel<<<(NN + 3) / 4, 256, 0, stream>>>(z_h, offs, csr, agg);
    gemm2_kernel<<<(NN + 63) / 64, 256, 0, stream>>>(agg, Wg2, bg1, gamma, beta,
                                                     rmean, rvar, z2_h);
    gather2_kernel<<<(NN + 3) / 4, 256, 0, stream>>>(z2_h, offs, csr, bg2, out);
}

// Round 3
// 1079.155 us; speedup vs baseline: 2.1542x; 1.2490x over previous
//
#include <hip/hip_runtime.h>
#include <hip/hip_fp16.h>
#include <cstddef>

#define NN    100000
#define EE    1600000
#define F1D   512
#define F3D   128
#define HD    128
#define CD    64
#define SWc   0.2f
#define FWc   0.8f
#define BN_EPS 1e-5f

typedef _Float16 half8 __attribute__((ext_vector_type(8)));
typedef float f32x4 __attribute__((ext_vector_type(4)));

// ===========================================================================
// CSR build: deg-count -> single-block scan -> atomic-cursor fill
// ===========================================================================
__global__ __launch_bounds__(256) void count_kernel(
    const int* __restrict__ dst, int* __restrict__ deg)
{
    int e = blockIdx.x * 256 + threadIdx.x;
    if (e < EE) atomicAdd(&deg[dst[e]], 1);
}

__global__ __launch_bounds__(1024) void scan_kernel(
    int* __restrict__ offsets, int* __restrict__ cursor)
{
    const int T = 1024;
    const int tid = threadIdx.x;
    const int per = (NN + T - 1) / T;
    int lo = tid * per;
    int hi = lo + per; if (hi > NN) hi = NN; if (lo > NN) lo = NN;

    int sum = 0;
    for (int i = lo; i < hi; ++i) sum += offsets[i];

    __shared__ int sh[T];
    sh[tid] = sum;
    __syncthreads();
    for (int d = 1; d < T; d <<= 1) {
        int v = (tid >= d) ? sh[tid - d] : 0;
        __syncthreads();
        sh[tid] += v;
        __syncthreads();
    }
    int run = (tid == 0) ? 0 : sh[tid - 1];
    for (int i = lo; i < hi; ++i) {
        int d = offsets[i];
        offsets[i] = run;
        cursor[i]  = run;
        run += d;
    }
    if (tid == T - 1) offsets[NN] = run;
}

__global__ __launch_bounds__(256) void fill_kernel(
    const int* __restrict__ src, const int* __restrict__ dst,
    int* __restrict__ cursor, int* __restrict__ csr_src)
{
    int e = blockIdx.x * 256 + threadIdx.x;
    if (e < EE) {
        int d = dst[e];
        int pos = atomicAdd(&cursor[d], 1);
        csr_src[pos] = src[e];
    }
}

// ===========================================================================
// Prep: Wc_t[n=128][k=640] = f16(FW*W1^T | SW*W2^T); Wg1_t[n=128][k=128];
//       Wg2_t[n=64][k=128]; hbuf[128] = FW*b1 + SW*b2
// ===========================================================================
__global__ __launch_bounds__(256) void prep_kernel(
    const float* __restrict__ W1, const float* __restrict__ W2,
    const float* __restrict__ Wg1, const float* __restrict__ Wg2,
    const float* __restrict__ b1, const float* __restrict__ b2,
    _Float16* __restrict__ Wc_t, _Float16* __restrict__ Wg1_t,
    _Float16* __restrict__ Wg2_t, float* __restrict__ hbuf)
{
    int i = blockIdx.x * 256 + threadIdx.x;
    if (i < 128 * 640) {
        int n = i / 640, k = i % 640;
        float v = (k < F1D) ? FWc * W1[(size_t)k * HD + n]
                            : SWc * W2[(size_t)(k - F1D) * HD + n];
        Wc_t[i] = (_Float16)v;
    } else if (i < 128 * 640 + 128 * 128) {
        int j = i - 128 * 640; int n = j / 128, k = j % 128;
        Wg1_t[j] = (_Float16)Wg1[(size_t)k * HD + n];
    } else if (i < 128 * 640 + 128 * 128 + 64 * 128) {
        int j = i - 128 * 640 - 128 * 128; int n = j / 128, k = j % 128;
        Wg2_t[j] = (_Float16)Wg2[(size_t)k * CD + n];
    } else if (i < 128 * 640 + 128 * 128 + 64 * 128 + 128) {
        int j = i - (128 * 640 + 128 * 128 + 64 * 128);
        hbuf[j] = FWc * b1[j] + SWc * b2[j];
    }
}

// ===========================================================================
// GEMM1 (MFMA f16): h = [x1|x2] @ Wc + hb;  z = h @ Wg1   (z f16)
// Block 256 = 4 waves. Tile M=128, N=128, K=640 (BK=64). Wave: 32 rows x 128.
// ===========================================================================
__global__ __launch_bounds__(256) void gemm1_mfma(
    const float* __restrict__ x1, const float* __restrict__ x2,
    const _Float16* __restrict__ Wc_t, const _Float16* __restrict__ Wg1_t,
    const float* __restrict__ hbuf, _Float16* __restrict__ z)
{
    __shared__ __align__(16) _Float16 As[128][72];
    __shared__ __align__(16) _Float16 Bs[128][72];
    __shared__ __align__(16) _Float16 Hs[128][136];

    const int tid  = threadIdx.x;
    const int wave = tid >> 6;
    const int lane = tid & 63;
    const int quad = lane >> 4;
    const int l16  = lane & 15;
    const int row0 = blockIdx.x * 128;

    const int sr = tid >> 1;           // staging row 0..127
    const int sc = (tid & 1) * 32;     // staging col offset

    f32x4 acc[2][8];
    const f32x4 zero4 = {0.f, 0.f, 0.f, 0.f};
#pragma unroll
    for (int mi = 0; mi < 2; ++mi)
#pragma unroll
        for (int ni = 0; ni < 8; ++ni) acc[mi][ni] = zero4;

    // ---- Phase 1: h = X @ Wc over K=640 in 10 tiles of 64 ----
    for (int t = 0; t < 10; ++t) {
        const float* xp; int stride, kb;
        if (t < 8) { xp = x1; stride = F1D; kb = t * 64; }
        else       { xp = x2; stride = F3D; kb = (t - 8) * 64; }
        __syncthreads();
        {
            int gr = row0 + sr;
            if (gr < NN) {
                const float4* rp = (const float4*)(xp + (size_t)gr * stride + kb + sc);
#pragma unroll
                for (int i = 0; i < 4; ++i) {
                    float4 f0 = rp[2 * i];
                    float4 f1 = rp[2 * i + 1];
                    half8 hv = { (_Float16)f0.x, (_Float16)f0.y, (_Float16)f0.z, (_Float16)f0.w,
                                 (_Float16)f1.x, (_Float16)f1.y, (_Float16)f1.z, (_Float16)f1.w };
                    *(half8*)&As[sr][sc + i * 8] = hv;
                }
            } else {
                half8 zv = { (_Float16)0.f, (_Float16)0.f, (_Float16)0.f, (_Float16)0.f,
                             (_Float16)0.f, (_Float16)0.f, (_Float16)0.f, (_Float16)0.f };
#pragma unroll
                for (int i = 0; i < 4; ++i) *(half8*)&As[sr][sc + i * 8] = zv;
            }
            const _Float16* wp = Wc_t + (size_t)sr * 640 + t * 64 + sc;
#pragma unroll
            for (int i = 0; i < 4; ++i)
                *(half8*)&Bs[sr][sc + i * 8] = *(const half8*)(wp + i * 8);
        }
        __syncthreads();
#pragma unroll
        for (int ks = 0; ks < 2; ++ks) {
            half8 a[2], b[8];
#pragma unroll
            for (int mi = 0; mi < 2; ++mi)
                a[mi] = *(const half8*)&As[wave * 32 + mi * 16 + l16][ks * 32 + quad * 8];
#pragma unroll
            for (int ni = 0; ni < 8; ++ni)
                b[ni] = *(const half8*)&Bs[ni * 16 + l16][ks * 32 + quad * 8];
#pragma unroll
            for (int mi = 0; mi < 2; ++mi)
#pragma unroll
                for (int ni = 0; ni < 8; ++ni)
                    acc[mi][ni] = __builtin_amdgcn_mfma_f32_16x16x32_f16(
                        a[mi], b[ni], acc[mi][ni], 0, 0, 0);
        }
    }

    // ---- h + bias -> Hs (f16). C-layout: col=l16, row=quad*4+r. Writes are
    // wave-own rows [wave*32, wave*32+32): no cross-wave hazard. ----
    {
        float hbv[8];
#pragma unroll
        for (int ni = 0; ni < 8; ++ni) hbv[ni] = hbuf[ni * 16 + l16];
#pragma unroll
        for (int mi = 0; mi < 2; ++mi)
#pragma unroll
            for (int ni = 0; ni < 8; ++ni)
#pragma unroll
                for (int r = 0; r < 4; ++r)
                    Hs[wave * 32 + mi * 16 + quad * 4 + r][ni * 16 + l16] =
                        (_Float16)(acc[mi][ni][r] + hbv[ni]);
    }

    // ---- Phase 2: z = h @ Wg1, K=128 in 2 tiles of 64 (Bs reused) ----
#pragma unroll
    for (int mi = 0; mi < 2; ++mi)
#pragma unroll
        for (int ni = 0; ni < 8; ++ni) acc[mi][ni] = zero4;

    for (int t = 0; t < 2; ++t) {
        __syncthreads();
        {
            const _Float16* wp = Wg1_t + (size_t)sr * 128 + t * 64 + sc;
#pragma unroll
            for (int i = 0; i < 4; ++i)
                *(half8*)&Bs[sr][sc + i * 8] = *(const half8*)(wp + i * 8);
        }
        __syncthreads();
#pragma unroll
        for (int ks = 0; ks < 2; ++ks) {
            half8 a[2], b[8];
#pragma unroll
            for (int mi = 0; mi < 2; ++mi)
                a[mi] = *(const half8*)&Hs[wave * 32 + mi * 16 + l16][t * 64 + ks * 32 + quad * 8];
#pragma unroll
            for (int ni = 0; ni < 8; ++ni)
                b[ni] = *(const half8*)&Bs[ni * 16 + l16][ks * 32 + quad * 8];
#pragma unroll
            for (int mi = 0; mi < 2; ++mi)
#pragma unroll
                for (int ni = 0; ni < 8; ++ni)
                    acc[mi][ni] = __builtin_amdgcn_mfma_f32_16x16x32_f16(
                        a[mi], b[ni], acc[mi][ni], 0, 0, 0);
        }
    }

    // ---- z tile -> Hs (overwrite, wave-own rows), then coalesced store ----
#pragma unroll
    for (int mi = 0; mi < 2; ++mi)
#pragma unroll
        for (int ni = 0; ni < 8; ++ni)
#pragma unroll
            for (int r = 0; r < 4; ++r)
                Hs[wave * 32 + mi * 16 + quad * 4 + r][ni * 16 + l16] =
                    (_Float16)acc[mi][ni][r];
    __syncthreads();
    {
        int gr = row0 + sr;
        if (gr < NN) {
            int c0 = (tid & 1) * 64;
            _Float16* zp = z + (size_t)gr * HD + c0;
#pragma unroll
            for (int i = 0; i < 8; ++i)
                *(half8*)(zp + i * 8) = *(const half8*)&Hs[sr][c0 + i * 8];
        }
    }
}

// ===========================================================================
// GEMM2 (MFMA f16, fused BN+ReLU): z2 = relu(agg*s + t) @ Wg2   (z2 f16)
// Block 256 = 4 waves. Tile M=128, N=64, K=128 (BK=64). Wave: 32 rows x 64.
// ===========================================================================
__global__ __launch_bounds__(256) void gemm2_mfma(
    const float* __restrict__ agg, const _Float16* __restrict__ Wg2_t,
    const float* __restrict__ bg1, const float* __restrict__ gamma,
    const float* __restrict__ beta, const float* __restrict__ rmean,
    const float* __restrict__ rvar, _Float16* __restrict__ z2)
{
    __shared__ __align__(16) _Float16 As[128][72];
    __shared__ __align__(16) _Float16 Bs[64][72];
    __shared__ float sS[HD], sT[HD];

    const int tid = threadIdx.x;
    if (tid < HD) {
        float s = gamma[tid] * rsqrtf(rvar[tid] + BN_EPS);
        sS[tid] = s;
        sT[tid] = (bg1[tid] - rmean[tid]) * s + beta[tid];
    }
    __syncthreads();

    const int wave = tid >> 6;
    const int lane = tid & 63;
    const int quad = lane >> 4;
    const int l16  = lane & 15;
    const int row0 = blockIdx.x * 128;
    const int sr = tid >> 1;
    const int sc = (tid & 1) * 32;

    f32x4 acc[2][4];
    const f32x4 zero4 = {0.f, 0.f, 0.f, 0.f};
#pragma unroll
    for (int mi = 0; mi < 2; ++mi)
#pragma unroll
        for (int ni = 0; ni < 4; ++ni) acc[mi][ni] = zero4;

    for (int t = 0; t < 2; ++t) {
        __syncthreads();
        {
            int gr = row0 + sr;
            if (gr < NN) {
                const float4* rp = (const float4*)(agg + (size_t)gr * HD + t * 64 + sc);
#pragma unroll
                for (int i = 0; i < 4; ++i) {
                    float4 f0 = rp[2 * i];
                    float4 f1 = rp[2 * i + 1];
                    int k = t * 64 + sc + i * 8;
                    float v0 = fmaxf(fmaf(f0.x, sS[k + 0], sT[k + 0]), 0.f);
                    float v1 = fmaxf(fmaf(f0.y, sS[k + 1], sT[k + 1]), 0.f);
                    float v2 = fmaxf(fmaf(f0.z, sS[k + 2], sT[k + 2]), 0.f);
                    float v3 = fmaxf(fmaf(f0.w, sS[k + 3], sT[k + 3]), 0.f);
                    float v4 = fmaxf(fmaf(f1.x, sS[k + 4], sT[k + 4]), 0.f);
                    float v5 = fmaxf(fmaf(f1.y, sS[k + 5], sT[k + 5]), 0.f);
                    float v6 = fmaxf(fmaf(f1.z, sS[k + 6], sT[k + 6]), 0.f);
                    float v7 = fmaxf(fmaf(f1.w, sS[k + 7], sT[k + 7]), 0.f);
                    half8 hv = { (_Float16)v0, (_Float16)v1, (_Float16)v2, (_Float16)v3,
                                 (_Float16)v4, (_Float16)v5, (_Float16)v6, (_Float16)v7 };
                    *(half8*)&As[sr][sc + i * 8] = hv;
                }
            } else {
                half8 zv = { (_Float16)0.f, (_Float16)0.f, (_Float16)0.f, (_Float16)0.f,
                             (_Float16)0.f, (_Float16)0.f, (_Float16)0.f, (_Float16)0.f };
#pragma unroll
                for (int i = 0; i < 4; ++i) *(half8*)&As[sr][sc + i * 8] = zv;
            }
            int n = tid >> 2, c = (tid & 3) * 16;
            const _Float16* wp = Wg2_t + (size_t)n * 128 + t * 64 + c;
            *(half8*)&Bs[n][c]     = *(const half8*)wp;
            *(half8*)&Bs[n][c + 8] = *(const half8*)(wp + 8);
        }
        __syncthreads();
#pragma unroll
        for (int ks = 0; ks < 2; ++ks) {
            half8 a[2], b[4];
#pragma unroll
            for (int mi = 0; mi < 2; ++mi)
                a[mi] = *(const half8*)&As[wave * 32 + mi * 16 + l16][ks * 32 + quad * 8];
#pragma unroll
            for (int ni = 0; ni < 4; ++ni)
                b[ni] = *(const half8*)&Bs[ni * 16 + l16][ks * 32 + quad * 8];
#pragma unroll
            for (int mi = 0; mi < 2; ++mi)
#pragma unroll
                for (int ni = 0; ni < 4; ++ni)
                    acc[mi][ni] = __builtin_amdgcn_mfma_f32_16x16x32_f16(
                        a[mi], b[ni], acc[mi][ni], 0, 0, 0);
        }
    }

    __syncthreads();
    // z2 tile -> As reuse (wave-own rows), then coalesced store
#pragma unroll
    for (int mi = 0; mi < 2; ++mi)
#pragma unroll
        for (int ni = 0; ni < 4; ++ni)
#pragma unroll
            for (int r = 0; r < 4; ++r)
                As[wave * 32 + mi * 16 + quad * 4 + r][ni * 16 + l16] =
                    (_Float16)acc[mi][ni][r];
    __syncthreads();
    {
        int gr = row0 + sr;
        if (gr < NN) {
            _Float16* zp = z2 + (size_t)gr * CD + sc;
            *(half8*)(zp)      = *(const half8*)&As[sr][sc];
            *(half8*)(zp + 8)  = *(const half8*)&As[sr][sc + 8];
            *(half8*)(zp + 16) = *(const half8*)&As[sr][sc + 16];
            *(half8*)(zp + 24) = *(const half8*)&As[sr][sc + 24];
        }
    }
}

// ===========================================================================
// Gather 1: agg[n] = sum_{e: dst[e]=n} z[src[e]]  (1 wave/node)
// ===========================================================================
__global__ __launch_bounds__(256) void gather1_kernel(
    const __half* __restrict__ z, const int* __restrict__ offsets,
    const int* __restrict__ csr_src, float* __restrict__ agg)
{
    int node = blockIdx.x * 4 + (threadIdx.x >> 6);
    if (node >= NN) return;
    int lane = threadIdx.x & 63;
    int beg = offsets[node], end = offsets[node + 1];
    float sx = 0.f, sy = 0.f;
    for (int j = beg; j < end; ++j) {
        int s = csr_src[j];
        __half2 v = *(const __half2*)(z + (size_t)s * HD + lane * 2);
        float2 f = __half22float2(v);
        sx += f.x; sy += f.y;
    }
    *(float2*)(agg + (size_t)node * HD + lane * 2) = make_float2(sx, sy);
}

// ===========================================================================
// Gather 2: out[n] = bg2 + sum_{e: dst[e]=n} z2[src[e]]  (1 wave/node)
// ===========================================================================
__global__ __launch_bounds__(256) void gather2_kernel(
    const __half* __restrict__ z2, const int* __restrict__ offsets,
    const int* __restrict__ csr_src, const float* __restrict__ bg2,
    float* __restrict__ out)
{
    int node = blockIdx.x * 4 + (threadIdx.x >> 6);
    if (node >= NN) return;
    int lane = threadIdx.x & 63;
    int beg = offsets[node], end = offsets[node + 1];
    float s = bg2[lane];
    for (int j = beg; j < end; ++j) {
        int sn = csr_src[j];
        s += __half2float(z2[(size_t)sn * CD + lane]);
    }
    out[(size_t)node * CD + lane] = s;
}

// ===========================================================================
extern "C" void kernel_launch(void* const* d_in, const int* in_sizes, int n_in,
                              void* d_out, int out_size, void* d_ws, size_t ws_size,
                              hipStream_t stream)
{
    const float* x1    = (const float*)d_in[0];
    const float* x2    = (const float*)d_in[1];
    const int*   ei    = (const int*)d_in[2];
    const float* W1    = (const float*)d_in[3];
    const float* b1    = (const float*)d_in[4];
    const float* W2    = (const float*)d_in[5];
    const float* b2    = (const float*)d_in[6];
    const float* Wg1   = (const float*)d_in[7];
    const float* bg1   = (const float*)d_in[8];
    const float* Wg2   = (const float*)d_in[9];
    const float* bg2   = (const float*)d_in[10];
    const float* gamma = (const float*)d_in[11];
    const float* beta  = (const float*)d_in[12];
    const float* rmean = (const float*)d_in[13];
    const float* rvar  = (const float*)d_in[14];
    float* out = (float*)d_out;

    // ---- workspace layout (all chunks 16B-aligned), ~84.3 MB ----
    char* p = (char*)d_ws;
    _Float16* z_h  = (_Float16*)p; p += (size_t)NN * HD * sizeof(_Float16);   // 25.6 MB
    float*  agg    = (float*)p;    p += (size_t)NN * HD * sizeof(float);      // 51.2 MB
    int*    csr    = (int*)p;      p += (size_t)EE * sizeof(int);             // 6.4 MB
    int*    offs   = (int*)p;      p += (size_t)(NN + 16) * sizeof(int);
    int*    curs   = (int*)p;      p += (size_t)(NN + 16) * sizeof(int);
    _Float16* Wc_t = (_Float16*)p; p += (size_t)128 * 640 * sizeof(_Float16); // 160 KB
    _Float16* Wg1t = (_Float16*)p; p += (size_t)128 * 128 * sizeof(_Float16);
    _Float16* Wg2t = (_Float16*)p; p += (size_t)64 * 128 * sizeof(_Float16);
    float*  hbuf   = (float*)p;    p += 128 * sizeof(float);
    _Float16* z2_h = z_h;   // overlay: z dead after gather1

    const int* src = ei;
    const int* dst = ei + EE;

    // Weight prep (f16, transposed, scales folded)
    prep_kernel<<<(128 * 640 + 128 * 128 + 64 * 128 + 128 + 255) / 256, 256, 0, stream>>>(
        W1, W2, Wg1, Wg2, b1, b2, Wc_t, Wg1t, Wg2t, hbuf);

    // CSR build
    hipMemsetAsync(offs, 0, (size_t)(NN + 1) * sizeof(int), stream);
    count_kernel<<<(EE + 255) / 256, 256, 0, stream>>>(dst, offs);
    scan_kernel<<<1, 1024, 0, stream>>>(offs, curs);
    fill_kernel<<<(EE + 255) / 256, 256, 0, stream>>>(src, dst, curs, csr);

    // Pipeline
    gemm1_mfma<<<(NN + 127) / 128, 256, 0, stream>>>(x1, x2, Wc_t, Wg1t, hbuf, z_h);
    gather1_kernel<<<(NN + 3) / 4, 256, 0, stream>>>((const __half*)z_h, offs, csr, agg);
    gemm2_mfma<<<(NN + 127) / 128, 256, 0, stream>>>(agg, Wg2t, bg1, gamma, beta,
                                                     rmean, rvar, z2_h);
    gather2_kernel<<<(NN + 3) / 4, 256, 0, stream>>>((const __half*)z2_h, offs, csr, bg2, out);
}

// Round 4
// 863.133 us; speedup vs baseline: 2.6933x; 1.2503x over previous
//
#include <hip/hip_runtime.h>
#include <hip/hip_fp16.h>
#include <cstddef>

#define NN    100000
#define EE    1600000
#define F1D   512
#define F3D   128
#define HD    128
#define CD    64
#define SWc   0.2f
#define FWc   0.8f
#define BN_EPS 1e-5f

#define SCAN_B 1024
#define NB ((NN + SCAN_B - 1) / SCAN_B)   // 98

typedef _Float16 half8 __attribute__((ext_vector_type(8)));
typedef float f32x4 __attribute__((ext_vector_type(4)));

// ===========================================================================
// CSR build: deg-count -> 3-phase multi-block scan -> atomic-cursor fill
// ===========================================================================
__global__ __launch_bounds__(256) void count_kernel(
    const int* __restrict__ dst, int* __restrict__ deg)
{
    int e = blockIdx.x * 256 + threadIdx.x;
    if (e < EE) atomicAdd(&deg[dst[e]], 1);
}

// Phase A: per-block reduce of deg -> partials[NB]
__global__ __launch_bounds__(SCAN_B) void scan_partial_kernel(
    const int* __restrict__ deg, int* __restrict__ partials)
{
    __shared__ int sh[SCAN_B / 64];
    int i = blockIdx.x * SCAN_B + threadIdx.x;
    int v = (i < NN) ? deg[i] : 0;
#pragma unroll
    for (int d = 32; d > 0; d >>= 1) v += __shfl_down(v, d, 64);
    int lane = threadIdx.x & 63, wv = threadIdx.x >> 6;
    if (lane == 0) sh[wv] = v;
    __syncthreads();
    if (threadIdx.x < SCAN_B / 64) {
        int s = sh[threadIdx.x];
#pragma unroll
        for (int d = SCAN_B / 128; d > 0; d >>= 1) s += __shfl_down(s, d, 64);
        if (threadIdx.x == 0) partials[blockIdx.x] = s;
    }
}

// Phase B: 1 small block exclusive-scans partials in place; writes offsets[NN]
__global__ __launch_bounds__(128) void scan_base_kernel(
    int* __restrict__ partials, int* __restrict__ offsets)
{
    __shared__ int sh[128];
    int t = threadIdx.x;
    int v = (t < NB) ? partials[t] : 0;
    sh[t] = v;
    __syncthreads();
    for (int d = 1; d < 128; d <<= 1) {
        int u = (t >= d) ? sh[t - d] : 0;
        __syncthreads();
        sh[t] += u;
        __syncthreads();
    }
    if (t < NB) partials[t] = sh[t] - v;           // exclusive base per block
    if (t == NB - 1) offsets[NN] = sh[t];          // total == EE
}

// Phase C: per-block Hillis-Steele scan + base -> offsets & cursor
__global__ __launch_bounds__(SCAN_B) void scan_apply_kernel(
    const int* __restrict__ deg, const int* __restrict__ partials,
    int* __restrict__ offsets, int* __restrict__ cursor)
{
    __shared__ int sh[SCAN_B];
    int t = threadIdx.x;
    int i = blockIdx.x * SCAN_B + t;
    int v = (i < NN) ? deg[i] : 0;
    sh[t] = v;
    __syncthreads();
    for (int d = 1; d < SCAN_B; d <<= 1) {
        int u = (t >= d) ? sh[t - d] : 0;
        __syncthreads();
        sh[t] += u;
        __syncthreads();
    }
    if (i < NN) {
        int excl = sh[t] - v + partials[blockIdx.x];
        offsets[i] = excl;
        cursor[i]  = excl;
    }
}

__global__ __launch_bounds__(256) void fill_kernel(
    const int* __restrict__ src, const int* __restrict__ dst,
    int* __restrict__ cursor, int* __restrict__ csr_src)
{
    int e = blockIdx.x * 256 + threadIdx.x;
    if (e < EE) {
        int d = dst[e];
        int pos = atomicAdd(&cursor[d], 1);
        csr_src[pos] = src[e];
    }
}

// ===========================================================================
// Prep: Wc_t[n=128][k=640] = f16(FW*W1^T | SW*W2^T); Wg1_t[n=128][k=128];
//       Wg2_t[n=64][k=128]; hbuf[128] = FW*b1 + SW*b2
// ===========================================================================
__global__ __launch_bounds__(256) void prep_kernel(
    const float* __restrict__ W1, const float* __restrict__ W2,
    const float* __restrict__ Wg1, const float* __restrict__ Wg2,
    const float* __restrict__ b1, const float* __restrict__ b2,
    _Float16* __restrict__ Wc_t, _Float16* __restrict__ Wg1_t,
    _Float16* __restrict__ Wg2_t, float* __restrict__ hbuf)
{
    int i = blockIdx.x * 256 + threadIdx.x;
    if (i < 128 * 640) {
        int n = i / 640, k = i % 640;
        float v = (k < F1D) ? FWc * W1[(size_t)k * HD + n]
                            : SWc * W2[(size_t)(k - F1D) * HD + n];
        Wc_t[i] = (_Float16)v;
    } else if (i < 128 * 640 + 128 * 128) {
        int j = i - 128 * 640; int n = j / 128, k = j % 128;
        Wg1_t[j] = (_Float16)Wg1[(size_t)k * HD + n];
    } else if (i < 128 * 640 + 128 * 128 + 64 * 128) {
        int j = i - 128 * 640 - 128 * 128; int n = j / 128, k = j % 128;
        Wg2_t[j] = (_Float16)Wg2[(size_t)k * CD + n];
    } else if (i < 128 * 640 + 128 * 128 + 64 * 128 + 128) {
        int j = i - (128 * 640 + 128 * 128 + 64 * 128);
        hbuf[j] = FWc * b1[j] + SWc * b2[j];
    }
}

// ===========================================================================
// GEMM1 (MFMA f16): h = [x1|x2] @ Wc + hb;  z = h @ Wg1   (z f16)
// Block 256 = 4 waves. Tile M=128, N=128, K=640 (BK=64). Wave: 32 rows x 128.
// ===========================================================================
__global__ __launch_bounds__(256) void gemm1_mfma(
    const float* __restrict__ x1, const float* __restrict__ x2,
    const _Float16* __restrict__ Wc_t, const _Float16* __restrict__ Wg1_t,
    const float* __restrict__ hbuf, _Float16* __restrict__ z)
{
    __shared__ __align__(16) _Float16 As[128][72];
    __shared__ __align__(16) _Float16 Bs[128][72];
    __shared__ __align__(16) _Float16 Hs[128][136];

    const int tid  = threadIdx.x;
    const int wave = tid >> 6;
    const int lane = tid & 63;
    const int quad = lane >> 4;
    const int l16  = lane & 15;
    const int row0 = blockIdx.x * 128;

    const int sr = tid >> 1;           // staging row 0..127
    const int sc = (tid & 1) * 32;     // staging col offset

    f32x4 acc[2][8];
    const f32x4 zero4 = {0.f, 0.f, 0.f, 0.f};
#pragma unroll
    for (int mi = 0; mi < 2; ++mi)
#pragma unroll
        for (int ni = 0; ni < 8; ++ni) acc[mi][ni] = zero4;

    // ---- Phase 1: h = X @ Wc over K=640 in 10 tiles of 64 ----
    for (int t = 0; t < 10; ++t) {
        const float* xp; int stride, kb;
        if (t < 8) { xp = x1; stride = F1D; kb = t * 64; }
        else       { xp = x2; stride = F3D; kb = (t - 8) * 64; }
        __syncthreads();
        {
            int gr = row0 + sr;
            if (gr < NN) {
                const float4* rp = (const float4*)(xp + (size_t)gr * stride + kb + sc);
#pragma unroll
                for (int i = 0; i < 4; ++i) {
                    float4 f0 = rp[2 * i];
                    float4 f1 = rp[2 * i + 1];
                    half8 hv = { (_Float16)f0.x, (_Float16)f0.y, (_Float16)f0.z, (_Float16)f0.w,
                                 (_Float16)f1.x, (_Float16)f1.y, (_Float16)f1.z, (_Float16)f1.w };
                    *(half8*)&As[sr][sc + i * 8] = hv;
                }
            } else {
                half8 zv = { (_Float16)0.f, (_Float16)0.f, (_Float16)0.f, (_Float16)0.f,
                             (_Float16)0.f, (_Float16)0.f, (_Float16)0.f, (_Float16)0.f };
#pragma unroll
                for (int i = 0; i < 4; ++i) *(half8*)&As[sr][sc + i * 8] = zv;
            }
            const _Float16* wp = Wc_t + (size_t)sr * 640 + t * 64 + sc;
#pragma unroll
            for (int i = 0; i < 4; ++i)
                *(half8*)&Bs[sr][sc + i * 8] = *(const half8*)(wp + i * 8);
        }
        __syncthreads();
#pragma unroll
        for (int ks = 0; ks < 2; ++ks) {
            half8 a[2], b[8];
#pragma unroll
            for (int mi = 0; mi < 2; ++mi)
                a[mi] = *(const half8*)&As[wave * 32 + mi * 16 + l16][ks * 32 + quad * 8];
#pragma unroll
            for (int ni = 0; ni < 8; ++ni)
                b[ni] = *(const half8*)&Bs[ni * 16 + l16][ks * 32 + quad * 8];
#pragma unroll
            for (int mi = 0; mi < 2; ++mi)
#pragma unroll
                for (int ni = 0; ni < 8; ++ni)
                    acc[mi][ni] = __builtin_amdgcn_mfma_f32_16x16x32_f16(
                        a[mi], b[ni], acc[mi][ni], 0, 0, 0);
        }
    }

    // ---- h + bias -> Hs (f16). C-layout: col=l16, row=quad*4+r. ----
    {
        float hbv[8];
#pragma unroll
        for (int ni = 0; ni < 8; ++ni) hbv[ni] = hbuf[ni * 16 + l16];
#pragma unroll
        for (int mi = 0; mi < 2; ++mi)
#pragma unroll
            for (int ni = 0; ni < 8; ++ni)
#pragma unroll
                for (int r = 0; r < 4; ++r)
                    Hs[wave * 32 + mi * 16 + quad * 4 + r][ni * 16 + l16] =
                        (_Float16)(acc[mi][ni][r] + hbv[ni]);
    }

    // ---- Phase 2: z = h @ Wg1, K=128 in 2 tiles of 64 (Bs reused) ----
#pragma unroll
    for (int mi = 0; mi < 2; ++mi)
#pragma unroll
        for (int ni = 0; ni < 8; ++ni) acc[mi][ni] = zero4;

    for (int t = 0; t < 2; ++t) {
        __syncthreads();
        {
            const _Float16* wp = Wg1_t + (size_t)sr * 128 + t * 64 + sc;
#pragma unroll
            for (int i = 0; i < 4; ++i)
                *(half8*)&Bs[sr][sc + i * 8] = *(const half8*)(wp + i * 8);
        }
        __syncthreads();
#pragma unroll
        for (int ks = 0; ks < 2; ++ks) {
            half8 a[2], b[8];
#pragma unroll
            for (int mi = 0; mi < 2; ++mi)
                a[mi] = *(const half8*)&Hs[wave * 32 + mi * 16 + l16][t * 64 + ks * 32 + quad * 8];
#pragma unroll
            for (int ni = 0; ni < 8; ++ni)
                b[ni] = *(const half8*)&Bs[ni * 16 + l16][ks * 32 + quad * 8];
#pragma unroll
            for (int mi = 0; mi < 2; ++mi)
#pragma unroll
                for (int ni = 0; ni < 8; ++ni)
                    acc[mi][ni] = __builtin_amdgcn_mfma_f32_16x16x32_f16(
                        a[mi], b[ni], acc[mi][ni], 0, 0, 0);
        }
    }

    // ---- z tile -> Hs (overwrite, wave-own rows), then coalesced store ----
#pragma unroll
    for (int mi = 0; mi < 2; ++mi)
#pragma unroll
        for (int ni = 0; ni < 8; ++ni)
#pragma unroll
            for (int r = 0; r < 4; ++r)
                Hs[wave * 32 + mi * 16 + quad * 4 + r][ni * 16 + l16] =
                    (_Float16)acc[mi][ni][r];
    __syncthreads();
    {
        int gr = row0 + sr;
        if (gr < NN) {
            int c0 = (tid & 1) * 64;
            _Float16* zp = z + (size_t)gr * HD + c0;
#pragma unroll
            for (int i = 0; i < 8; ++i)
                *(half8*)(zp + i * 8) = *(const half8*)&Hs[sr][c0 + i * 8];
        }
    }
}

// ===========================================================================
// GEMM2 (MFMA f16, fused BN+ReLU): z2 = relu(agg*s + t) @ Wg2   (z2 f16)
// ===========================================================================
__global__ __launch_bounds__(256) void gemm2_mfma(
    const float* __restrict__ agg, const _Float16* __restrict__ Wg2_t,
    const float* __restrict__ bg1, const float* __restrict__ gamma,
    const float* __restrict__ beta, const float* __restrict__ rmean,
    const float* __restrict__ rvar, _Float16* __restrict__ z2)
{
    __shared__ __align__(16) _Float16 As[128][72];
    __shared__ __align__(16) _Float16 Bs[64][72];
    __shared__ float sS[HD], sT[HD];

    const int tid = threadIdx.x;
    if (tid < HD) {
        float s = gamma[tid] * rsqrtf(rvar[tid] + BN_EPS);
        sS[tid] = s;
        sT[tid] = (bg1[tid] - rmean[tid]) * s + beta[tid];
    }
    __syncthreads();

    const int wave = tid >> 6;
    const int lane = tid & 63;
    const int quad = lane >> 4;
    const int l16  = lane & 15;
    const int row0 = blockIdx.x * 128;
    const int sr = tid >> 1;
    const int sc = (tid & 1) * 32;

    f32x4 acc[2][4];
    const f32x4 zero4 = {0.f, 0.f, 0.f, 0.f};
#pragma unroll
    for (int mi = 0; mi < 2; ++mi)
#pragma unroll
        for (int ni = 0; ni < 4; ++ni) acc[mi][ni] = zero4;

    for (int t = 0; t < 2; ++t) {
        __syncthreads();
        {
            int gr = row0 + sr;
            if (gr < NN) {
                const float4* rp = (const float4*)(agg + (size_t)gr * HD + t * 64 + sc);
#pragma unroll
                for (int i = 0; i < 4; ++i) {
                    float4 f0 = rp[2 * i];
                    float4 f1 = rp[2 * i + 1];
                    int k = t * 64 + sc + i * 8;
                    float v0 = fmaxf(fmaf(f0.x, sS[k + 0], sT[k + 0]), 0.f);
                    float v1 = fmaxf(fmaf(f0.y, sS[k + 1], sT[k + 1]), 0.f);
                    float v2 = fmaxf(fmaf(f0.z, sS[k + 2], sT[k + 2]), 0.f);
                    float v3 = fmaxf(fmaf(f0.w, sS[k + 3], sT[k + 3]), 0.f);
                    float v4 = fmaxf(fmaf(f1.x, sS[k + 4], sT[k + 4]), 0.f);
                    float v5 = fmaxf(fmaf(f1.y, sS[k + 5], sT[k + 5]), 0.f);
                    float v6 = fmaxf(fmaf(f1.z, sS[k + 6], sT[k + 6]), 0.f);
                    float v7 = fmaxf(fmaf(f1.w, sS[k + 7], sT[k + 7]), 0.f);
                    half8 hv = { (_Float16)v0, (_Float16)v1, (_Float16)v2, (_Float16)v3,
                                 (_Float16)v4, (_Float16)v5, (_Float16)v6, (_Float16)v7 };
                    *(half8*)&As[sr][sc + i * 8] = hv;
                }
            } else {
                half8 zv = { (_Float16)0.f, (_Float16)0.f, (_Float16)0.f, (_Float16)0.f,
                             (_Float16)0.f, (_Float16)0.f, (_Float16)0.f, (_Float16)0.f };
#pragma unroll
                for (int i = 0; i < 4; ++i) *(half8*)&As[sr][sc + i * 8] = zv;
            }
            int n = tid >> 2, c = (tid & 3) * 16;
            const _Float16* wp = Wg2_t + (size_t)n * 128 + t * 64 + c;
            *(half8*)&Bs[n][c]     = *(const half8*)wp;
            *(half8*)&Bs[n][c + 8] = *(const half8*)(wp + 8);
        }
        __syncthreads();
#pragma unroll
        for (int ks = 0; ks < 2; ++ks) {
            half8 a[2], b[4];
#pragma unroll
            for (int mi = 0; mi < 2; ++mi)
                a[mi] = *(const half8*)&As[wave * 32 + mi * 16 + l16][ks * 32 + quad * 8];
#pragma unroll
            for (int ni = 0; ni < 4; ++ni)
                b[ni] = *(const half8*)&Bs[ni * 16 + l16][ks * 32 + quad * 8];
#pragma unroll
            for (int mi = 0; mi < 2; ++mi)
#pragma unroll
                for (int ni = 0; ni < 4; ++ni)
                    acc[mi][ni] = __builtin_amdgcn_mfma_f32_16x16x32_f16(
                        a[mi], b[ni], acc[mi][ni], 0, 0, 0);
        }
    }

    __syncthreads();
    // z2 tile -> As reuse (wave-own rows), then coalesced store
#pragma unroll
    for (int mi = 0; mi < 2; ++mi)
#pragma unroll
        for (int ni = 0; ni < 4; ++ni)
#pragma unroll
            for (int r = 0; r < 4; ++r)
                As[wave * 32 + mi * 16 + quad * 4 + r][ni * 16 + l16] =
                    (_Float16)acc[mi][ni][r];
    __syncthreads();
    {
        int gr = row0 + sr;
        if (gr < NN) {
            _Float16* zp = z2 + (size_t)gr * CD + sc;
            *(half8*)(zp)      = *(const half8*)&As[sr][sc];
            *(half8*)(zp + 8)  = *(const half8*)&As[sr][sc + 8];
            *(half8*)(zp + 16) = *(const half8*)&As[sr][sc + 16];
            *(half8*)(zp + 24) = *(const half8*)&As[sr][sc + 24];
        }
    }
}

// ===========================================================================
// Gather 1: agg[n] = sum_{e: dst[e]=n} z[src[e]]  (1 wave/node)
// ===========================================================================
__global__ __launch_bounds__(256) void gather1_kernel(
    const __half* __restrict__ z, const int* __restrict__ offsets,
    const int* __restrict__ csr_src, float* __restrict__ agg)
{
    int node = blockIdx.x * 4 + (threadIdx.x >> 6);
    if (node >= NN) return;
    int lane = threadIdx.x & 63;
    int beg = offsets[node], end = offsets[node + 1];
    float sx = 0.f, sy = 0.f;
    for (int j = beg; j < end; ++j) {
        int s = csr_src[j];
        __half2 v = *(const __half2*)(z + (size_t)s * HD + lane * 2);
        float2 f = __half22float2(v);
        sx += f.x; sy += f.y;
    }
    *(float2*)(agg + (size_t)node * HD + lane * 2) = make_float2(sx, sy);
}

// ===========================================================================
// Gather 2: out[n] = bg2 + sum_{e: dst[e]=n} z2[src[e]]  (1 wave/node)
// ===========================================================================
__global__ __launch_bounds__(256) void gather2_kernel(
    const __half* __restrict__ z2, const int* __restrict__ offsets,
    const int* __restrict__ csr_src, const float* __restrict__ bg2,
    float* __restrict__ out)
{
    int node = blockIdx.x * 4 + (threadIdx.x >> 6);
    if (node >= NN) return;
    int lane = threadIdx.x & 63;
    int beg = offsets[node], end = offsets[node + 1];
    float s = bg2[lane];
    for (int j = beg; j < end; ++j) {
        int sn = csr_src[j];
        s += __half2float(z2[(size_t)sn * CD + lane]);
    }
    out[(size_t)node * CD + lane] = s;
}

// ===========================================================================
extern "C" void kernel_launch(void* const* d_in, const int* in_sizes, int n_in,
                              void* d_out, int out_size, void* d_ws, size_t ws_size,
                              hipStream_t stream)
{
    const float* x1    = (const float*)d_in[0];
    const float* x2    = (const float*)d_in[1];
    const int*   ei    = (const int*)d_in[2];
    const float* W1    = (const float*)d_in[3];
    const float* b1    = (const float*)d_in[4];
    const float* W2    = (const float*)d_in[5];
    const float* b2    = (const float*)d_in[6];
    const float* Wg1   = (const float*)d_in[7];
    const float* bg1   = (const float*)d_in[8];
    const float* Wg2   = (const float*)d_in[9];
    const float* bg2   = (const float*)d_in[10];
    const float* gamma = (const float*)d_in[11];
    const float* beta  = (const float*)d_in[12];
    const float* rmean = (const float*)d_in[13];
    const float* rvar  = (const float*)d_in[14];
    float* out = (float*)d_out;

    // ---- workspace layout (all chunks 16B-aligned), ~85 MB ----
    char* p = (char*)d_ws;
    _Float16* z_h  = (_Float16*)p; p += (size_t)NN * HD * sizeof(_Float16);   // 25.6 MB
    float*  agg    = (float*)p;    p += (size_t)NN * HD * sizeof(float);      // 51.2 MB
    int*    csr    = (int*)p;      p += (size_t)EE * sizeof(int);             // 6.4 MB
    int*    offs   = (int*)p;      p += (size_t)(NN + 16) * sizeof(int);
    int*    curs   = (int*)p;      p += (size_t)(NN + 16) * sizeof(int);
    int*    deg    = (int*)p;      p += (size_t)(NN + 16) * sizeof(int);
    int*    parts  = (int*)p;      p += (size_t)(NB + 16) * sizeof(int);
    _Float16* Wc_t = (_Float16*)p; p += (size_t)128 * 640 * sizeof(_Float16); // 160 KB
    _Float16* Wg1t = (_Float16*)p; p += (size_t)128 * 128 * sizeof(_Float16);
    _Float16* Wg2t = (_Float16*)p; p += (size_t)64 * 128 * sizeof(_Float16);
    float*  hbuf   = (float*)p;    p += 128 * sizeof(float);
    _Float16* z2_h = z_h;   // overlay: z dead after gather1

    const int* src = ei;
    const int* dst = ei + EE;

    // Weight prep (f16, transposed, scales folded)
    prep_kernel<<<(128 * 640 + 128 * 128 + 64 * 128 + 128 + 255) / 256, 256, 0, stream>>>(
        W1, W2, Wg1, Wg2, b1, b2, Wc_t, Wg1t, Wg2t, hbuf);

    // CSR build
    hipMemsetAsync(deg, 0, (size_t)NN * sizeof(int), stream);
    count_kernel<<<(EE + 255) / 256, 256, 0, stream>>>(dst, deg);
    scan_partial_kernel<<<NB, SCAN_B, 0, stream>>>(deg, parts);
    scan_base_kernel<<<1, 128, 0, stream>>>(parts, offs);
    scan_apply_kernel<<<NB, SCAN_B, 0, stream>>>(deg, parts, offs, curs);
    fill_kernel<<<(EE + 255) / 256, 256, 0, stream>>>(src, dst, curs, csr);

    // Pipeline
    gemm1_mfma<<<(NN + 127) / 128, 256, 0, stream>>>(x1, x2, Wc_t, Wg1t, hbuf, z_h);
    gather1_kernel<<<(NN + 3) / 4, 256, 0, stream>>>((const __half*)z_h, offs, csr, agg);
    gemm2_mfma<<<(NN + 127) / 128, 256, 0, stream>>>(agg, Wg2t, bg1, gamma, beta,
                                                     rmean, rvar, z2_h);
    gather2_kernel<<<(NN + 3) / 4, 256, 0, stream>>>((const __half*)z2_h, offs, csr, bg2, out);
}

// Round 5
// 697.672 us; speedup vs baseline: 3.3321x; 1.2372x over previous
//
#include <hip/hip_runtime.h>
#include <hip/hip_fp16.h>
#include <cstddef>

#define NN    100000
#define EE    1600000
#define F1D   512
#define F3D   128
#define HD    128
#define CD    64
#define SWc   0.2f
#define FWc   0.8f
#define BN_EPS 1e-5f

#define SCAN_B 1024
#define NB ((NN + SCAN_B - 1) / SCAN_B)   // 98

typedef _Float16 half8 __attribute__((ext_vector_type(8)));
typedef float f32x4 __attribute__((ext_vector_type(4)));

// ===========================================================================
// CSR build: deg-count -> 3-phase multi-block scan -> atomic-cursor fill
// ===========================================================================
__global__ __launch_bounds__(256) void count_kernel(
    const int* __restrict__ dst, int* __restrict__ deg)
{
    int e = blockIdx.x * 256 + threadIdx.x;
    if (e < EE) atomicAdd(&deg[dst[e]], 1);
}

// Phase A: per-block reduce of deg -> partials[NB]
__global__ __launch_bounds__(SCAN_B) void scan_partial_kernel(
    const int* __restrict__ deg, int* __restrict__ partials)
{
    __shared__ int sh[SCAN_B / 64];
    int i = blockIdx.x * SCAN_B + threadIdx.x;
    int v = (i < NN) ? deg[i] : 0;
#pragma unroll
    for (int d = 32; d > 0; d >>= 1) v += __shfl_down(v, d, 64);
    int lane = threadIdx.x & 63, wv = threadIdx.x >> 6;
    if (lane == 0) sh[wv] = v;
    __syncthreads();
    if (threadIdx.x < SCAN_B / 64) {
        int s = sh[threadIdx.x];
#pragma unroll
        for (int d = SCAN_B / 128; d > 0; d >>= 1) s += __shfl_down(s, d, 64);
        if (threadIdx.x == 0) partials[blockIdx.x] = s;
    }
}

// Phase B: 1 small block exclusive-scans partials in place; writes offsets[NN]
__global__ __launch_bounds__(128) void scan_base_kernel(
    int* __restrict__ partials, int* __restrict__ offsets)
{
    __shared__ int sh[128];
    int t = threadIdx.x;
    int v = (t < NB) ? partials[t] : 0;
    sh[t] = v;
    __syncthreads();
    for (int d = 1; d < 128; d <<= 1) {
        int u = (t >= d) ? sh[t - d] : 0;
        __syncthreads();
        sh[t] += u;
        __syncthreads();
    }
    if (t < NB) partials[t] = sh[t] - v;           // exclusive base per block
    if (t == NB - 1) offsets[NN] = sh[t];          // total == EE
}

// Phase C: per-block Hillis-Steele scan + base -> offsets & cursor
__global__ __launch_bounds__(SCAN_B) void scan_apply_kernel(
    const int* __restrict__ deg, const int* __restrict__ partials,
    int* __restrict__ offsets, int* __restrict__ cursor)
{
    __shared__ int sh[SCAN_B];
    int t = threadIdx.x;
    int i = blockIdx.x * SCAN_B + t;
    int v = (i < NN) ? deg[i] : 0;
    sh[t] = v;
    __syncthreads();
    for (int d = 1; d < SCAN_B; d <<= 1) {
        int u = (t >= d) ? sh[t - d] : 0;
        __syncthreads();
        sh[t] += u;
        __syncthreads();
    }
    if (i < NN) {
        int excl = sh[t] - v + partials[blockIdx.x];
        offsets[i] = excl;
        cursor[i]  = excl;
    }
}

__global__ __launch_bounds__(256) void fill_kernel(
    const int* __restrict__ src, const int* __restrict__ dst,
    int* __restrict__ cursor, int* __restrict__ csr_src)
{
    int e = blockIdx.x * 256 + threadIdx.x;
    if (e < EE) {
        int d = dst[e];
        int pos = atomicAdd(&cursor[d], 1);
        csr_src[pos] = src[e];
    }
}

// ===========================================================================
// Prep: Wc_t[n=128][k=640] = f16(FW*W1^T | SW*W2^T); Wg1_t[n=128][k=128];
//       Wg2_t[n=64][k=128]; hbuf[128] = FW*b1 + SW*b2
// ===========================================================================
__global__ __launch_bounds__(256) void prep_kernel(
    const float* __restrict__ W1, const float* __restrict__ W2,
    const float* __restrict__ Wg1, const float* __restrict__ Wg2,
    const float* __restrict__ b1, const float* __restrict__ b2,
    _Float16* __restrict__ Wc_t, _Float16* __restrict__ Wg1_t,
    _Float16* __restrict__ Wg2_t, float* __restrict__ hbuf)
{
    int i = blockIdx.x * 256 + threadIdx.x;
    if (i < 128 * 640) {
        int n = i / 640, k = i % 640;
        float v = (k < F1D) ? FWc * W1[(size_t)k * HD + n]
                            : SWc * W2[(size_t)(k - F1D) * HD + n];
        Wc_t[i] = (_Float16)v;
    } else if (i < 128 * 640 + 128 * 128) {
        int j = i - 128 * 640; int n = j / 128, k = j % 128;
        Wg1_t[j] = (_Float16)Wg1[(size_t)k * HD + n];
    } else if (i < 128 * 640 + 128 * 128 + 64 * 128) {
        int j = i - 128 * 640 - 128 * 128; int n = j / 128, k = j % 128;
        Wg2_t[j] = (_Float16)Wg2[(size_t)k * CD + n];
    } else if (i < 128 * 640 + 128 * 128 + 64 * 128 + 128) {
        int j = i - (128 * 640 + 128 * 128 + 64 * 128);
        hbuf[j] = FWc * b1[j] + SWc * b2[j];
    }
}

// ===========================================================================
// GEMM1 (MFMA f16): h = [x1|x2] @ Wc + hb;  z = h @ Wg1   (z f16)
// Block 256 = 4 waves. Tile M=128, N=128, K=640 (BK=64). Wave: 32 rows x 128.
// ===========================================================================
__global__ __launch_bounds__(256) void gemm1_mfma(
    const float* __restrict__ x1, const float* __restrict__ x2,
    const _Float16* __restrict__ Wc_t, const _Float16* __restrict__ Wg1_t,
    const float* __restrict__ hbuf, _Float16* __restrict__ z)
{
    __shared__ __align__(16) _Float16 As[128][72];
    __shared__ __align__(16) _Float16 Bs[128][72];
    __shared__ __align__(16) _Float16 Hs[128][136];

    const int tid  = threadIdx.x;
    const int wave = tid >> 6;
    const int lane = tid & 63;
    const int quad = lane >> 4;
    const int l16  = lane & 15;
    const int row0 = blockIdx.x * 128;

    const int sr = tid >> 1;           // staging row 0..127
    const int sc = (tid & 1) * 32;     // staging col offset

    f32x4 acc[2][8];
    const f32x4 zero4 = {0.f, 0.f, 0.f, 0.f};
#pragma unroll
    for (int mi = 0; mi < 2; ++mi)
#pragma unroll
        for (int ni = 0; ni < 8; ++ni) acc[mi][ni] = zero4;

    // ---- Phase 1: h = X @ Wc over K=640 in 10 tiles of 64 ----
    for (int t = 0; t < 10; ++t) {
        const float* xp; int stride, kb;
        if (t < 8) { xp = x1; stride = F1D; kb = t * 64; }
        else       { xp = x2; stride = F3D; kb = (t - 8) * 64; }
        __syncthreads();
        {
            int gr = row0 + sr;
            if (gr < NN) {
                const float4* rp = (const float4*)(xp + (size_t)gr * stride + kb + sc);
#pragma unroll
                for (int i = 0; i < 4; ++i) {
                    float4 f0 = rp[2 * i];
                    float4 f1 = rp[2 * i + 1];
                    half8 hv = { (_Float16)f0.x, (_Float16)f0.y, (_Float16)f0.z, (_Float16)f0.w,
                                 (_Float16)f1.x, (_Float16)f1.y, (_Float16)f1.z, (_Float16)f1.w };
                    *(half8*)&As[sr][sc + i * 8] = hv;
                }
            } else {
                half8 zv = { (_Float16)0.f, (_Float16)0.f, (_Float16)0.f, (_Float16)0.f,
                             (_Float16)0.f, (_Float16)0.f, (_Float16)0.f, (_Float16)0.f };
#pragma unroll
                for (int i = 0; i < 4; ++i) *(half8*)&As[sr][sc + i * 8] = zv;
            }
            const _Float16* wp = Wc_t + (size_t)sr * 640 + t * 64 + sc;
#pragma unroll
            for (int i = 0; i < 4; ++i)
                *(half8*)&Bs[sr][sc + i * 8] = *(const half8*)(wp + i * 8);
        }
        __syncthreads();
#pragma unroll
        for (int ks = 0; ks < 2; ++ks) {
            half8 a[2], b[8];
#pragma unroll
            for (int mi = 0; mi < 2; ++mi)
                a[mi] = *(const half8*)&As[wave * 32 + mi * 16 + l16][ks * 32 + quad * 8];
#pragma unroll
            for (int ni = 0; ni < 8; ++ni)
                b[ni] = *(const half8*)&Bs[ni * 16 + l16][ks * 32 + quad * 8];
#pragma unroll
            for (int mi = 0; mi < 2; ++mi)
#pragma unroll
                for (int ni = 0; ni < 8; ++ni)
                    acc[mi][ni] = __builtin_amdgcn_mfma_f32_16x16x32_f16(
                        a[mi], b[ni], acc[mi][ni], 0, 0, 0);
        }
    }

    // ---- h + bias -> Hs (f16). C-layout: col=l16, row=quad*4+r. ----
    {
        float hbv[8];
#pragma unroll
        for (int ni = 0; ni < 8; ++ni) hbv[ni] = hbuf[ni * 16 + l16];
#pragma unroll
        for (int mi = 0; mi < 2; ++mi)
#pragma unroll
            for (int ni = 0; ni < 8; ++ni)
#pragma unroll
                for (int r = 0; r < 4; ++r)
                    Hs[wave * 32 + mi * 16 + quad * 4 + r][ni * 16 + l16] =
                        (_Float16)(acc[mi][ni][r] + hbv[ni]);
    }

    // ---- Phase 2: z = h @ Wg1, K=128 in 2 tiles of 64 (Bs reused) ----
#pragma unroll
    for (int mi = 0; mi < 2; ++mi)
#pragma unroll
        for (int ni = 0; ni < 8; ++ni) acc[mi][ni] = zero4;

    for (int t = 0; t < 2; ++t) {
        __syncthreads();
        {
            const _Float16* wp = Wg1_t + (size_t)sr * 128 + t * 64 + sc;
#pragma unroll
            for (int i = 0; i < 4; ++i)
                *(half8*)&Bs[sr][sc + i * 8] = *(const half8*)(wp + i * 8);
        }
        __syncthreads();
#pragma unroll
        for (int ks = 0; ks < 2; ++ks) {
            half8 a[2], b[8];
#pragma unroll
            for (int mi = 0; mi < 2; ++mi)
                a[mi] = *(const half8*)&Hs[wave * 32 + mi * 16 + l16][t * 64 + ks * 32 + quad * 8];
#pragma unroll
            for (int ni = 0; ni < 8; ++ni)
                b[ni] = *(const half8*)&Bs[ni * 16 + l16][ks * 32 + quad * 8];
#pragma unroll
            for (int mi = 0; mi < 2; ++mi)
#pragma unroll
                for (int ni = 0; ni < 8; ++ni)
                    acc[mi][ni] = __builtin_amdgcn_mfma_f32_16x16x32_f16(
                        a[mi], b[ni], acc[mi][ni], 0, 0, 0);
        }
    }

    // ---- z tile -> Hs (overwrite, wave-own rows), then coalesced store ----
#pragma unroll
    for (int mi = 0; mi < 2; ++mi)
#pragma unroll
        for (int ni = 0; ni < 8; ++ni)
#pragma unroll
            for (int r = 0; r < 4; ++r)
                Hs[wave * 32 + mi * 16 + quad * 4 + r][ni * 16 + l16] =
                    (_Float16)acc[mi][ni][r];
    __syncthreads();
    {
        int gr = row0 + sr;
        if (gr < NN) {
            int c0 = (tid & 1) * 64;
            _Float16* zp = z + (size_t)gr * HD + c0;
#pragma unroll
            for (int i = 0; i < 8; ++i)
                *(half8*)(zp + i * 8) = *(const half8*)&Hs[sr][c0 + i * 8];
        }
    }
}

// ===========================================================================
// GEMM2 (MFMA f16, fused BN+ReLU): z2 = relu(agg*s + t) @ Wg2   (z2 f16)
// ===========================================================================
__global__ __launch_bounds__(256) void gemm2_mfma(
    const float* __restrict__ agg, const _Float16* __restrict__ Wg2_t,
    const float* __restrict__ bg1, const float* __restrict__ gamma,
    const float* __restrict__ beta, const float* __restrict__ rmean,
    const float* __restrict__ rvar, _Float16* __restrict__ z2)
{
    __shared__ __align__(16) _Float16 As[128][72];
    __shared__ __align__(16) _Float16 Bs[64][72];
    __shared__ float sS[HD], sT[HD];

    const int tid = threadIdx.x;
    if (tid < HD) {
        float s = gamma[tid] * rsqrtf(rvar[tid] + BN_EPS);
        sS[tid] = s;
        sT[tid] = (bg1[tid] - rmean[tid]) * s + beta[tid];
    }
    __syncthreads();

    const int wave = tid >> 6;
    const int lane = tid & 63;
    const int quad = lane >> 4;
    const int l16  = lane & 15;
    const int row0 = blockIdx.x * 128;
    const int sr = tid >> 1;
    const int sc = (tid & 1) * 32;

    f32x4 acc[2][4];
    const f32x4 zero4 = {0.f, 0.f, 0.f, 0.f};
#pragma unroll
    for (int mi = 0; mi < 2; ++mi)
#pragma unroll
        for (int ni = 0; ni < 4; ++ni) acc[mi][ni] = zero4;

    for (int t = 0; t < 2; ++t) {
        __syncthreads();
        {
            int gr = row0 + sr;
            if (gr < NN) {
                const float4* rp = (const float4*)(agg + (size_t)gr * HD + t * 64 + sc);
#pragma unroll
                for (int i = 0; i < 4; ++i) {
                    float4 f0 = rp[2 * i];
                    float4 f1 = rp[2 * i + 1];
                    int k = t * 64 + sc + i * 8;
                    float v0 = fmaxf(fmaf(f0.x, sS[k + 0], sT[k + 0]), 0.f);
                    float v1 = fmaxf(fmaf(f0.y, sS[k + 1], sT[k + 1]), 0.f);
                    float v2 = fmaxf(fmaf(f0.z, sS[k + 2], sT[k + 2]), 0.f);
                    float v3 = fmaxf(fmaf(f0.w, sS[k + 3], sT[k + 3]), 0.f);
                    float v4 = fmaxf(fmaf(f1.x, sS[k + 4], sT[k + 4]), 0.f);
                    float v5 = fmaxf(fmaf(f1.y, sS[k + 5], sT[k + 5]), 0.f);
                    float v6 = fmaxf(fmaf(f1.z, sS[k + 6], sT[k + 6]), 0.f);
                    float v7 = fmaxf(fmaf(f1.w, sS[k + 7], sT[k + 7]), 0.f);
                    half8 hv = { (_Float16)v0, (_Float16)v1, (_Float16)v2, (_Float16)v3,
                                 (_Float16)v4, (_Float16)v5, (_Float16)v6, (_Float16)v7 };
                    *(half8*)&As[sr][sc + i * 8] = hv;
                }
            } else {
                half8 zv = { (_Float16)0.f, (_Float16)0.f, (_Float16)0.f, (_Float16)0.f,
                             (_Float16)0.f, (_Float16)0.f, (_Float16)0.f, (_Float16)0.f };
#pragma unroll
                for (int i = 0; i < 4; ++i) *(half8*)&As[sr][sc + i * 8] = zv;
            }
            int n = tid >> 2, c = (tid & 3) * 16;
            const _Float16* wp = Wg2_t + (size_t)n * 128 + t * 64 + c;
            *(half8*)&Bs[n][c]     = *(const half8*)wp;
            *(half8*)&Bs[n][c + 8] = *(const half8*)(wp + 8);
        }
        __syncthreads();
#pragma unroll
        for (int ks = 0; ks < 2; ++ks) {
            half8 a[2], b[4];
#pragma unroll
            for (int mi = 0; mi < 2; ++mi)
                a[mi] = *(const half8*)&As[wave * 32 + mi * 16 + l16][ks * 32 + quad * 8];
#pragma unroll
            for (int ni = 0; ni < 4; ++ni)
                b[ni] = *(const half8*)&Bs[ni * 16 + l16][ks * 32 + quad * 8];
#pragma unroll
            for (int mi = 0; mi < 2; ++mi)
#pragma unroll
                for (int ni = 0; ni < 4; ++ni)
                    acc[mi][ni] = __builtin_amdgcn_mfma_f32_16x16x32_f16(
                        a[mi], b[ni], acc[mi][ni], 0, 0, 0);
        }
    }

    __syncthreads();
    // z2 tile -> As reuse (wave-own rows), then coalesced store
#pragma unroll
    for (int mi = 0; mi < 2; ++mi)
#pragma unroll
        for (int ni = 0; ni < 4; ++ni)
#pragma unroll
            for (int r = 0; r < 4; ++r)
                As[wave * 32 + mi * 16 + quad * 4 + r][ni * 16 + l16] =
                    (_Float16)acc[mi][ni][r];
    __syncthreads();
    {
        int gr = row0 + sr;
        if (gr < NN) {
            _Float16* zp = z2 + (size_t)gr * CD + sc;
            *(half8*)(zp)      = *(const half8*)&As[sr][sc];
            *(half8*)(zp + 8)  = *(const half8*)&As[sr][sc + 8];
            *(half8*)(zp + 16) = *(const half8*)&As[sr][sc + 16];
            *(half8*)(zp + 24) = *(const half8*)&As[sr][sc + 24];
        }
    }
}

// ===========================================================================
// Gather 1: agg[n] = sum_{e in CSR[n]} z[src[e]]  — 1 wave/node, 4 edges per
// load instruction (h = lane>>4 edge slot, fl = lane&15 -> 16B feature slice),
// 64 indices prefetched per chunk, #pragma unroll 4 => up to 16 edges in
// flight per wave.
// ===========================================================================
__global__ __launch_bounds__(256) void gather1_kernel(
    const _Float16* __restrict__ z, const int* __restrict__ offsets,
    const int* __restrict__ csr_src, float* __restrict__ agg)
{
    int node = blockIdx.x * 4 + (threadIdx.x >> 6);
    if (node >= NN) return;
    const int lane = threadIdx.x & 63;
    const int h  = lane >> 4;      // edge slot within quad
    const int fl = lane & 15;      // halves fl*8 .. fl*8+7 (16 B)

    int beg = offsets[node];
    int cnt = offsets[node + 1] - beg;

    float a0 = 0.f, a1 = 0.f, a2 = 0.f, a3 = 0.f;
    float a4 = 0.f, a5 = 0.f, a6 = 0.f, a7 = 0.f;

    for (int j0 = 0; j0 < cnt; j0 += 64) {
        int cntc = cnt - j0; if (cntc > 64) cntc = 64;
        int myidx = (lane < cntc) ? csr_src[beg + j0 + lane] : 0;
        int nq = (cntc + 3) >> 2;
#pragma unroll 4
        for (int i = 0; i < nq; ++i) {
            int e = i * 4 + h;
            int si = __shfl(myidx, e);
            float m = (e < cntc) ? 1.f : 0.f;
            float4 raw = *(const float4*)(z + (size_t)si * HD + fl * 8);
            const __half2* hp = (const __half2*)&raw;
            float2 f0 = __half22float2(hp[0]);
            float2 f1 = __half22float2(hp[1]);
            float2 f2 = __half22float2(hp[2]);
            float2 f3 = __half22float2(hp[3]);
            a0 = fmaf(m, f0.x, a0); a1 = fmaf(m, f0.y, a1);
            a2 = fmaf(m, f1.x, a2); a3 = fmaf(m, f1.y, a3);
            a4 = fmaf(m, f2.x, a4); a5 = fmaf(m, f2.y, a5);
            a6 = fmaf(m, f3.x, a6); a7 = fmaf(m, f3.y, a7);
        }
    }

    // reduce the 4 edge slots (lanes l, l^16, l^32, l^48)
    a0 += __shfl_xor(a0, 16); a1 += __shfl_xor(a1, 16);
    a2 += __shfl_xor(a2, 16); a3 += __shfl_xor(a3, 16);
    a4 += __shfl_xor(a4, 16); a5 += __shfl_xor(a5, 16);
    a6 += __shfl_xor(a6, 16); a7 += __shfl_xor(a7, 16);
    a0 += __shfl_xor(a0, 32); a1 += __shfl_xor(a1, 32);
    a2 += __shfl_xor(a2, 32); a3 += __shfl_xor(a3, 32);
    a4 += __shfl_xor(a4, 32); a5 += __shfl_xor(a5, 32);
    a6 += __shfl_xor(a6, 32); a7 += __shfl_xor(a7, 32);

    if (h == 0) {
        float* op = agg + (size_t)node * HD + fl * 8;
        float4 o0 = make_float4(a0, a1, a2, a3);
        float4 o1 = make_float4(a4, a5, a6, a7);
        *(float4*)op       = o0;
        *(float4*)(op + 4) = o1;
    }
}

// ===========================================================================
// Gather 2: out[n] = bg2 + sum_{e in CSR[n]} z2[src[e]] — same structure,
// 8 B feature slice per lane (row = 64 halves).
// ===========================================================================
__global__ __launch_bounds__(256) void gather2_kernel(
    const _Float16* __restrict__ z2, const int* __restrict__ offsets,
    const int* __restrict__ csr_src, const float* __restrict__ bg2,
    float* __restrict__ out)
{
    int node = blockIdx.x * 4 + (threadIdx.x >> 6);
    if (node >= NN) return;
    const int lane = threadIdx.x & 63;
    const int h  = lane >> 4;      // edge slot within quad
    const int fl = lane & 15;      // halves fl*4 .. fl*4+3 (8 B)

    int beg = offsets[node];
    int cnt = offsets[node + 1] - beg;

    float a0 = 0.f, a1 = 0.f, a2 = 0.f, a3 = 0.f;

    for (int j0 = 0; j0 < cnt; j0 += 64) {
        int cntc = cnt - j0; if (cntc > 64) cntc = 64;
        int myidx = (lane < cntc) ? csr_src[beg + j0 + lane] : 0;
        int nq = (cntc + 3) >> 2;
#pragma unroll 4
        for (int i = 0; i < nq; ++i) {
            int e = i * 4 + h;
            int si = __shfl(myidx, e);
            float m = (e < cntc) ? 1.f : 0.f;
            float2 raw = *(const float2*)(z2 + (size_t)si * CD + fl * 4);
            const __half2* hp = (const __half2*)&raw;
            float2 f0 = __half22float2(hp[0]);
            float2 f1 = __half22float2(hp[1]);
            a0 = fmaf(m, f0.x, a0); a1 = fmaf(m, f0.y, a1);
            a2 = fmaf(m, f1.x, a2); a3 = fmaf(m, f1.y, a3);
        }
    }

    a0 += __shfl_xor(a0, 16); a1 += __shfl_xor(a1, 16);
    a2 += __shfl_xor(a2, 16); a3 += __shfl_xor(a3, 16);
    a0 += __shfl_xor(a0, 32); a1 += __shfl_xor(a1, 32);
    a2 += __shfl_xor(a2, 32); a3 += __shfl_xor(a3, 32);

    if (h == 0) {
        float4 bv = *(const float4*)(bg2 + fl * 4);
        float4 o = make_float4(a0 + bv.x, a1 + bv.y, a2 + bv.z, a3 + bv.w);
        *(float4*)(out + (size_t)node * CD + fl * 4) = o;
    }
}

// ===========================================================================
extern "C" void kernel_launch(void* const* d_in, const int* in_sizes, int n_in,
                              void* d_out, int out_size, void* d_ws, size_t ws_size,
                              hipStream_t stream)
{
    const float* x1    = (const float*)d_in[0];
    const float* x2    = (const float*)d_in[1];
    const int*   ei    = (const int*)d_in[2];
    const float* W1    = (const float*)d_in[3];
    const float* b1    = (const float*)d_in[4];
    const float* W2    = (const float*)d_in[5];
    const float* b2    = (const float*)d_in[6];
    const float* Wg1   = (const float*)d_in[7];
    const float* bg1   = (const float*)d_in[8];
    const float* Wg2   = (const float*)d_in[9];
    const float* bg2   = (const float*)d_in[10];
    const float* gamma = (const float*)d_in[11];
    const float* beta  = (const float*)d_in[12];
    const float* rmean = (const float*)d_in[13];
    const float* rvar  = (const float*)d_in[14];
    float* out = (float*)d_out;

    // ---- workspace layout (all chunks 16B-aligned), ~85 MB ----
    char* p = (char*)d_ws;
    _Float16* z_h  = (_Float16*)p; p += (size_t)NN * HD * sizeof(_Float16);   // 25.6 MB
    float*  agg    = (float*)p;    p += (size_t)NN * HD * sizeof(float);      // 51.2 MB
    int*    csr    = (int*)p;      p += (size_t)EE * sizeof(int);             // 6.4 MB
    int*    offs   = (int*)p;      p += (size_t)(NN + 16) * sizeof(int);
    int*    curs   = (int*)p;      p += (size_t)(NN + 16) * sizeof(int);
    int*    deg    = (int*)p;      p += (size_t)(NN + 16) * sizeof(int);
    int*    parts  = (int*)p;      p += (size_t)(NB + 16) * sizeof(int);
    _Float16* Wc_t = (_Float16*)p; p += (size_t)128 * 640 * sizeof(_Float16); // 160 KB
    _Float16* Wg1t = (_Float16*)p; p += (size_t)128 * 128 * sizeof(_Float16);
    _Float16* Wg2t = (_Float16*)p; p += (size_t)64 * 128 * sizeof(_Float16);
    float*  hbuf   = (float*)p;    p += 128 * sizeof(float);
    _Float16* z2_h = z_h;   // overlay: z dead after gather1

    const int* src = ei;
    const int* dst = ei + EE;

    // Weight prep (f16, transposed, scales folded)
    prep_kernel<<<(128 * 640 + 128 * 128 + 64 * 128 + 128 + 255) / 256, 256, 0, stream>>>(
        W1, W2, Wg1, Wg2, b1, b2, Wc_t, Wg1t, Wg2t, hbuf);

    // CSR build
    hipMemsetAsync(deg, 0, (size_t)NN * sizeof(int), stream);
    count_kernel<<<(EE + 255) / 256, 256, 0, stream>>>(dst, deg);
    scan_partial_kernel<<<NB, SCAN_B, 0, stream>>>(deg, parts);
    scan_base_kernel<<<1, 128, 0, stream>>>(parts, offs);
    scan_apply_kernel<<<NB, SCAN_B, 0, stream>>>(deg, parts, offs, curs);
    fill_kernel<<<(EE + 255) / 256, 256, 0, stream>>>(src, dst, curs, csr);

    // Pipeline
    gemm1_mfma<<<(NN + 127) / 128, 256, 0, stream>>>(x1, x2, Wc_t, Wg1t, hbuf, z_h);
    gather1_kernel<<<(NN + 3) / 4, 256, 0, stream>>>(z_h, offs, csr, agg);
    gemm2_mfma<<<(NN + 127) / 128, 256, 0, stream>>>(agg, Wg2t, bg1, gamma, beta,
                                                     rmean, rvar, z2_h);
    gather2_kernel<<<(NN + 3) / 4, 256, 0, stream>>>(z2_h, offs, csr, bg2, out);
}